// Round 2
// baseline (5419.556 us; speedup 1.0000x reference)
//
#include <hip/hip_runtime.h>
#include <hip/hip_bf16.h>
#include <hip/hip_cooperative_groups.h>
#include <cstdint>
#include <cstddef>

namespace cg = cooperative_groups;

typedef __attribute__((ext_vector_type(8))) short short8;
typedef __attribute__((ext_vector_type(4))) float f32x4;
typedef unsigned short u16;

#define VOCAB 32000
#define EMB   512
#define HID   1024
#define GDIM  4096   // 4*HID
#define BATCH 16
#define SEQ   256
#define MTOT  4096   // BATCH*SEQ

static __device__ __forceinline__ u16 f2bf(float f) {
  unsigned u = __builtin_bit_cast(unsigned, f);
  u += 0x7fffu + ((u >> 16) & 1u);   // RNE
  return (u16)(u >> 16);
}

__global__ void cvt_bf16(const float* __restrict__ in, u16* __restrict__ out, long n) {
  long i = (long)blockIdx.x * blockDim.x + threadIdx.x;
  long stride = (long)gridDim.x * blockDim.x;
  for (; i < n; i += stride) out[i] = f2bf(in[i]);
}

__global__ void embed_gather(const int* __restrict__ x, const float* __restrict__ emb,
                             u16* __restrict__ A) {
  int m = blockIdx.x;                 // 0..4095  (m = b*SEQ + t)
  long base = (long)x[m] * EMB;
  for (int e = threadIdx.x; e < EMB; e += blockDim.x)
    A[(long)m * EMB + e] = f2bf(emb[base + e]);
}

// C[M][N] = A[M][K] * B[N][K]^T + bias[N], bf16 inputs, f32 out.
__global__ __launch_bounds__(256) void gemm_bt(
    const u16* __restrict__ A, const u16* __restrict__ B,
    const float* __restrict__ bias, float* __restrict__ C,
    int M, int N, int K)
{
  __shared__ u16 As[128 * 32];
  __shared__ u16 Bs[128 * 32];
  int tid  = threadIdx.x;
  int lane = tid & 63;
  int wid  = tid >> 6;
  int m0 = blockIdx.y * 128, n0 = blockIdx.x * 128;
  int wm = (wid >> 1) * 64, wn = (wid & 1) * 64;
  f32x4 acc[4][4] = {};

  int u0 = tid, u1 = tid + 256;              // staging slots in [0,512)
  int r0 = u0 >> 2, c0 = (u0 & 3) * 8;
  int r1 = u1 >> 2, c1 = (u1 & 3) * 8;

  int nk = K / 32;
  for (int kt = 0; kt < nk; ++kt) {
    int k = kt * 32;
    short8 va0 = *reinterpret_cast<const short8*>(A + (long)(m0 + r0) * K + k + c0);
    short8 va1 = *reinterpret_cast<const short8*>(A + (long)(m0 + r1) * K + k + c1);
    short8 vb0 = *reinterpret_cast<const short8*>(B + (long)(n0 + r0) * K + k + c0);
    short8 vb1 = *reinterpret_cast<const short8*>(B + (long)(n0 + r1) * K + k + c1);
    __syncthreads();                          // previous tile's LDS reads done
    reinterpret_cast<short8*>(As)[u0] = va0;
    reinterpret_cast<short8*>(As)[u1] = va1;
    reinterpret_cast<short8*>(Bs)[u0] = vb0;
    reinterpret_cast<short8*>(Bs)[u1] = vb1;
    __syncthreads();                          // writes visible
    short8 af[4], bf[4];
#pragma unroll
    for (int i = 0; i < 4; ++i) {
      af[i] = *reinterpret_cast<const short8*>(&As[(wm + i * 16 + (lane & 15)) * 32 + ((lane >> 4) << 3)]);
      bf[i] = *reinterpret_cast<const short8*>(&Bs[(wn + i * 16 + (lane & 15)) * 32 + ((lane >> 4) << 3)]);
    }
#pragma unroll
    for (int i = 0; i < 4; ++i)
#pragma unroll
      for (int j = 0; j < 4; ++j)
        acc[i][j] = __builtin_amdgcn_mfma_f32_16x16x32_bf16(af[i], bf[j], acc[i][j], 0, 0, 0);
  }

#pragma unroll
  for (int i = 0; i < 4; ++i) {
    int m = m0 + wm + i * 16 + ((lane >> 4) << 2);
#pragma unroll
    for (int j = 0; j < 4; ++j) {
      int n = n0 + wn + j * 16 + (lane & 15);
      float bv = bias[n];
#pragma unroll
      for (int jj = 0; jj < 4; ++jj)
        C[(long)(m + jj) * N + n] = acc[i][j][jj] + bv;
    }
  }
}

// Persistent LSTM: 64 blocks x 256 threads (cooperative). Block owns h-cols
// [blk*16, blk*16+16). W_hh slice (4 gates x 16 cols x 1024 K, 128 KiB bf16)
// lives in LDS for all 256 steps, XOR-swizzled against ds_read_b128 bank
// conflicts. Cell state in one register per thread. Grid barrier per step.
__global__ __launch_bounds__(256, 1) void lstm_persist(
    const float* __restrict__ xg, const u16* __restrict__ Whh,
    const float* __restrict__ b_hh, u16* __restrict__ h_buf,
    u16* __restrict__ h_all)
{
  __shared__ u16 Wlds[4 * 16 * 1024] __attribute__((aligned(16)));  // 128 KiB
  __shared__ float gates[4][16][16];                                //   4 KiB

  int tid = threadIdx.x;
  int g = tid >> 6, lane = tid & 63;
  int col0 = blockIdx.x * 16;

  // ---- stage Whh slice into LDS once (swizzled) ----
  for (int idx = tid; idx < 64 * 128; idx += 256) {
    int rl = idx >> 7;          // local row 0..63 = gate*16 + col
    int ch = idx & 127;         // 16-byte chunk within the 1024-u16 row
    int gg = rl >> 4, cc = rl & 15;
    short8 v = *reinterpret_cast<const short8*>(
        Whh + ((long)(gg * HID + col0 + cc) * HID + ch * 8));
    unsigned byte = ((unsigned)rl << 11) | ((unsigned)ch << 4);
    byte ^= ((byte >> 11) & 7u) << 4;
    *reinterpret_cast<short8*>(reinterpret_cast<char*>(Wlds) + byte) = v;
  }

  int eb = tid >> 4, ec = tid & 15;       // elementwise thread = (batch, col)
  h_buf[eb * HID + col0 + ec] = 0;        // h0 = 0 (own slice, both buffers same step-0 read)
  float creg = 0.f;

  int r  = lane & 15;                     // MFMA row (batch for A, gate-col for B)
  int ko = (lane >> 4) << 3;              // k offset within 32-wide K step
  unsigned lbase = (((unsigned)(g * 16 + r)) << 11) | ((unsigned)ko << 1);
  unsigned sw = ((lbase >> 11) & 7u) << 4;
  char* ldsb = reinterpret_cast<char*>(Wlds);

  // hoisted per-thread constants
  float bhv = b_hh[g * HID + col0 + (lane & 15)];
  const float* xgp[4];
#pragma unroll
  for (int j = 0; j < 4; ++j) {
    int batch = ((lane >> 4) << 2) + j;
    xgp[j] = xg + (long)batch * SEQ * GDIM + g * HID + col0 + (lane & 15);
  }
  const short8* ap0 = reinterpret_cast<const short8*>(h_buf + r * HID + ko);
  const short8* ap1 = reinterpret_cast<const short8*>(h_buf + BATCH * HID + r * HID + ko);
  u16* hn0 = h_buf + eb * HID + col0 + ec;                 // written when t even
  u16* hn1 = h_buf + BATCH * HID + eb * HID + col0 + ec;
  u16* hap = h_all + (long)eb * SEQ * HID + col0 + ec;

  cg::grid_group grid = cg::this_grid();
  __threadfence();
  grid.sync();

  for (int t = 0; t < SEQ; ++t) {
    const short8* ap = (t & 1) ? ap1 : ap0;
    f32x4 a0 = {}, a1 = {}, a2 = {}, a3 = {};
#pragma unroll
    for (int kk = 0; kk < 32; kk += 4) {
      short8 av0 = ap[(kk + 0) * 4];
      short8 av1 = ap[(kk + 1) * 4];
      short8 av2 = ap[(kk + 2) * 4];
      short8 av3 = ap[(kk + 3) * 4];
      short8 bv0 = *reinterpret_cast<const short8*>(ldsb + ((lbase + (kk + 0) * 64) ^ sw));
      short8 bv1 = *reinterpret_cast<const short8*>(ldsb + ((lbase + (kk + 1) * 64) ^ sw));
      short8 bv2 = *reinterpret_cast<const short8*>(ldsb + ((lbase + (kk + 2) * 64) ^ sw));
      short8 bv3 = *reinterpret_cast<const short8*>(ldsb + ((lbase + (kk + 3) * 64) ^ sw));
      a0 = __builtin_amdgcn_mfma_f32_16x16x32_bf16(av0, bv0, a0, 0, 0, 0);
      a1 = __builtin_amdgcn_mfma_f32_16x16x32_bf16(av1, bv1, a1, 0, 0, 0);
      a2 = __builtin_amdgcn_mfma_f32_16x16x32_bf16(av2, bv2, a2, 0, 0, 0);
      a3 = __builtin_amdgcn_mfma_f32_16x16x32_bf16(av3, bv3, a3, 0, 0, 0);
    }
    f32x4 acc = (a0 + a1) + (a2 + a3);

#pragma unroll
    for (int j = 0; j < 4; ++j) {
      int batch = ((lane >> 4) << 2) + j;
      float pre = acc[j] + xgp[j][(long)t * GDIM] + bhv;
      gates[g][batch][lane & 15] = pre;
    }
    __syncthreads();

    float i_ = gates[0][eb][ec], f_ = gates[1][eb][ec];
    float g_ = gates[2][eb][ec], o_ = gates[3][eb][ec];
    i_ = 1.f / (1.f + __expf(-i_));
    f_ = 1.f / (1.f + __expf(-f_));
    g_ = tanhf(g_);
    o_ = 1.f / (1.f + __expf(-o_));
    float cn = f_ * creg + i_ * g_;
    creg = cn;
    u16 hbf = f2bf(o_ * tanhf(cn));
    *((t & 1) ? hn0 : hn1) = hbf;           // write the OTHER buffer (t+1 reads it)
    hap[(long)t * HID] = hbf;

    __threadfence();
    grid.sync();
  }
}

extern "C" void kernel_launch(void* const* d_in, const int* in_sizes, int n_in,
                              void* d_out, int out_size, void* d_ws, size_t ws_size,
                              hipStream_t stream) {
  const int*   x      = (const int*)d_in[0];
  const float* emb    = (const float*)d_in[1];
  const float* W_ih   = (const float*)d_in[2];
  const float* W_hh   = (const float*)d_in[3];
  const float* b_ih   = (const float*)d_in[4];
  const float* b_hh   = (const float*)d_in[5];
  const float* head_W = (const float*)d_in[6];
  const float* head_b = (const float*)d_in[7];
  float* out = (float*)d_out;

  char* ws = (char*)d_ws;
  size_t off = 0;
  auto alloc = [&](size_t bytes) -> void* {
    void* p = ws + off;
    off += (bytes + 255) & ~(size_t)255;
    return p;
  };
  u16*   Aemb   = (u16*)alloc((size_t)MTOT * EMB * 2);     //  4 MiB
  u16*   Wih_b  = (u16*)alloc((size_t)GDIM * EMB * 2);     //  4 MiB
  u16*   Whh_b  = (u16*)alloc((size_t)GDIM * HID * 2);     //  8 MiB
  u16*   HW_b   = (u16*)alloc((size_t)VOCAB * HID * 2);    // 62.5 MiB
  float* xg     = (float*)alloc((size_t)MTOT * GDIM * 4);  // 64 MiB
  u16*   h_all  = (u16*)alloc((size_t)MTOT * HID * 2);     //  8 MiB
  u16*   h_buf  = (u16*)alloc((size_t)2 * BATCH * HID * 2);

  cvt_bf16<<<2048, 256, 0, stream>>>(W_ih, Wih_b, (long)GDIM * EMB);
  cvt_bf16<<<2048, 256, 0, stream>>>(W_hh, Whh_b, (long)GDIM * HID);
  cvt_bf16<<<4096, 256, 0, stream>>>(head_W, HW_b, (long)VOCAB * HID);
  embed_gather<<<MTOT, 256, 0, stream>>>(x, emb, Aemb);

  gemm_bt<<<dim3(GDIM / 128, MTOT / 128), 256, 0, stream>>>(
      Aemb, Wih_b, b_ih, xg, MTOT, GDIM, EMB);

  {
    const float* xgc = xg;
    const u16* whc = Whh_b;
    void* args[] = {(void*)&xgc, (void*)&whc, (void*)&b_hh,
                    (void*)&h_buf, (void*)&h_all};
    hipLaunchCooperativeKernel((const void*)lstm_persist, dim3(64), dim3(256),
                               args, 0, stream);
  }

  gemm_bt<<<dim3(VOCAB / 128, MTOT / 128), 256, 0, stream>>>(
      h_all, HW_b, head_b, out, MTOT, VOCAB, HID);
}

// Round 3
// 2885.468 us; speedup vs baseline: 1.8782x; 1.8782x over previous
//
#include <hip/hip_runtime.h>
#include <hip/hip_bf16.h>
#include <cstdint>
#include <cstddef>

typedef __attribute__((ext_vector_type(8))) short short8;
typedef __attribute__((ext_vector_type(4))) float f32x4;
typedef __attribute__((ext_vector_type(4))) float f4;
typedef __attribute__((ext_vector_type(4))) short s4;
typedef __attribute__((ext_vector_type(2))) unsigned long long u64x2;
typedef unsigned short u16;
typedef unsigned long long u64;

#define VOCAB 32000
#define EMB   512
#define HID   1024
#define GDIM  4096   // 4*HID
#define BATCH 16
#define SEQ   256
#define MTOT  4096   // BATCH*SEQ
#define NBLK  64     // lstm blocks

static __device__ __forceinline__ u16 f2bf(float f) {
  unsigned u = __builtin_bit_cast(unsigned, f);
  u += 0x7fffu + ((u >> 16) & 1u);   // RNE
  return (u16)(u >> 16);
}

__global__ void cvt_bf16_v4(const float* __restrict__ in, u16* __restrict__ out, long n4) {
  long i = (long)blockIdx.x * blockDim.x + threadIdx.x;
  long stride = (long)gridDim.x * blockDim.x;
  for (; i < n4; i += stride) {
    f4 v = reinterpret_cast<const f4*>(in)[i];
    s4 o;
#pragma unroll
    for (int j = 0; j < 4; ++j) o[j] = (short)f2bf(v[j]);
    reinterpret_cast<s4*>(out)[i] = o;
  }
}

__global__ void embed_gather(const int* __restrict__ x, const float* __restrict__ emb,
                             u16* __restrict__ A) {
  int m = blockIdx.x;                 // m = b*SEQ + t
  long base = (long)x[m] * EMB;
  int e4 = threadIdx.x;               // 0..127, 4 elems each
  f4 v = reinterpret_cast<const f4*>(emb + base)[e4];
  s4 o;
#pragma unroll
  for (int j = 0; j < 4; ++j) o[j] = (short)f2bf(v[j]);
  reinterpret_cast<s4*>(A + (long)m * EMB)[e4] = o;
}

static __device__ __forceinline__ void gload_lds16(const void* g, void* l) {
  __builtin_amdgcn_global_load_lds(
      (const __attribute__((address_space(1))) void*)g,
      (__attribute__((address_space(3))) void*)l, 16, 0, 0);
}

// C = A[M][K] * B[N][K]^T + bias[N]. bf16 in, f32 out. 128x128 tile, BK=32,
// global_load_lds width-16 staging (m97 structure).
// TXG=1: m encodes b*SEQ+t; write C at row (t*BATCH+b) -> time-major xg.
template<int TXG>
__global__ __launch_bounds__(256) void gemm_bt(
    const u16* __restrict__ A, const u16* __restrict__ B,
    const float* __restrict__ bias, float* __restrict__ C,
    int M, int N, int K)
{
  __shared__ u16 As[128 * 32];
  __shared__ u16 Bs[128 * 32];
  int tid  = threadIdx.x;
  int lane = tid & 63;
  int wid  = tid >> 6;
  int m0 = blockIdx.y * 128, n0 = blockIdx.x * 128;
  int wm = (wid >> 1) * 64, wn = (wid & 1) * 64;
  f32x4 acc[4][4] = {};

  // staging: chunk c in [0,512) <-> row c>>2, 8-elem col group c&3
  int c0 = wid * 128 + lane;
  int c1 = c0 + 64;
  const u16* ga0 = A + (long)(m0 + (c0 >> 2)) * K + (c0 & 3) * 8;
  const u16* ga1 = A + (long)(m0 + (c1 >> 2)) * K + (c1 & 3) * 8;
  const u16* gb0 = B + (long)(n0 + (c0 >> 2)) * K + (c0 & 3) * 8;
  const u16* gb1 = B + (long)(n0 + (c1 >> 2)) * K + (c1 & 3) * 8;
  u16* la0 = As + wid * 1024;       // wave-uniform LDS dst (lane*16B implicit)
  u16* la1 = la0 + 512;
  u16* lb0 = Bs + wid * 1024;
  u16* lb1 = lb0 + 512;

  for (int kt = 0; kt < K; kt += 32) {
    __syncthreads();                          // prior tile's LDS reads done
    gload_lds16(ga0 + kt, la0);
    gload_lds16(ga1 + kt, la1);
    gload_lds16(gb0 + kt, lb0);
    gload_lds16(gb1 + kt, lb1);
    __syncthreads();                          // vmcnt drain -> data visible
    short8 af[4], bf[4];
#pragma unroll
    for (int i = 0; i < 4; ++i) {
      af[i] = *reinterpret_cast<const short8*>(&As[(wm + i * 16 + (lane & 15)) * 32 + ((lane >> 4) << 3)]);
      bf[i] = *reinterpret_cast<const short8*>(&Bs[(wn + i * 16 + (lane & 15)) * 32 + ((lane >> 4) << 3)]);
    }
#pragma unroll
    for (int i = 0; i < 4; ++i)
#pragma unroll
      for (int j = 0; j < 4; ++j)
        acc[i][j] = __builtin_amdgcn_mfma_f32_16x16x32_bf16(af[i], bf[j], acc[i][j], 0, 0, 0);
  }

#pragma unroll
  for (int i = 0; i < 4; ++i) {
    int m = m0 + wm + i * 16 + ((lane >> 4) << 2);
#pragma unroll
    for (int j = 0; j < 4; ++j) {
      int n = n0 + wn + j * 16 + (lane & 15);
      float bv = bias[n];
#pragma unroll
      for (int jj = 0; jj < 4; ++jj) {
        int mm = m + jj;
        long row;
        if constexpr (TXG) {
          row = (long)(mm & (SEQ - 1)) * BATCH + (mm >> 8);  // t*B + b
        } else {
          row = mm;
        }
        C[row * N + n] = acc[i][j][jj] + bv;
      }
    }
  }
}

// Persistent LSTM, 64 blocks x 256 threads. W_hh slice in LDS (128 KiB,
// XOR-swizzled). Cross-block h exchange via agent-scope atomics (bypass
// non-coherent XCD L2s); custom monotonic barrier (1 atomicAdd + spin per
// block per step). xg is time-major [T][B][4H].
__global__ __launch_bounds__(256, 1) void lstm_persist(
    const float* __restrict__ xg, const u16* __restrict__ Whh,
    const float* __restrict__ b_hh, u16* __restrict__ h_buf,
    u16* __restrict__ h_all, unsigned* __restrict__ bar)
{
  __shared__ u16 Wlds[4 * 16 * 1024] __attribute__((aligned(16)));  // 128 KiB
  __shared__ float gates[4][16][16];
  __shared__ u16 htile[16][16];

  int tid = threadIdx.x;
  int g = tid >> 6, lane = tid & 63;
  int col0 = blockIdx.x * 16;

  // ---- stage Whh slice into LDS once (swizzled) ----
  for (int idx = tid; idx < 64 * 128; idx += 256) {
    int rl = idx >> 7;          // local row 0..63 = gate*16 + col
    int ch = idx & 127;
    int gg = rl >> 4, cc = rl & 15;
    short8 v = *reinterpret_cast<const short8*>(
        Whh + ((long)(gg * HID + col0 + cc) * HID + ch * 8));
    unsigned byte = ((unsigned)rl << 11) | ((unsigned)ch << 4);
    byte ^= ((byte >> 11) & 7u) << 4;
    *reinterpret_cast<short8*>(reinterpret_cast<char*>(Wlds) + byte) = v;
  }

  int r  = lane & 15;
  int ko = (lane >> 4) << 3;
  unsigned lbase = (((unsigned)(g * 16 + r)) << 11) | ((unsigned)ko << 1);
  unsigned sw = ((lbase >> 11) & 7u) << 4;
  char* ldsb = reinterpret_cast<char*>(Wlds);

  float bhv = b_hh[g * HID + col0 + (lane & 15)];

  u64* hb64 = reinterpret_cast<u64*>(h_buf);
  const int hofs = (r * HID + ko) >> 2;        // u64 units
  const int buf1 = (BATCH * HID) >> 2;

  int eb = tid >> 4, ec = tid & 15;
  u16* hap = h_all + (long)eb * SEQ * HID + col0 + ec;
  float creg = 0.f;

  // h0 = 0 into buffer 0 (coherent stores)
  if (tid < 64) {
    int b = tid >> 2, c4 = (tid & 3) * 4;
    __hip_atomic_store(&hb64[(b * HID + col0 + c4) >> 2], (u64)0,
                       __ATOMIC_RELAXED, __HIP_MEMORY_SCOPE_AGENT);
  }

  unsigned tgt = NBLK;
  auto gbar = [&]() {
    __syncthreads();   // drains this block's coherent stores (vmcnt 0) first
    if (tid == 0) {
      __hip_atomic_fetch_add(bar, 1u, __ATOMIC_RELAXED, __HIP_MEMORY_SCOPE_AGENT);
      while (__hip_atomic_load(bar, __ATOMIC_RELAXED, __HIP_MEMORY_SCOPE_AGENT) < tgt)
        __builtin_amdgcn_s_sleep(1);
    }
    __syncthreads();
    tgt += NBLK;
  };

  gbar();

  for (int t = 0; t < SEQ; ++t) {
    // xg for this step (time-major: contiguous 256 KB slab per t)
    float xv[4];
#pragma unroll
    for (int j = 0; j < 4; ++j) {
      int batch = ((lane >> 4) << 2) + j;
      xv[j] = xg[((long)t * BATCH + batch) * GDIM + g * HID + col0 + (lane & 15)];
    }

    const u64* hp = hb64 + ((t & 1) ? buf1 : 0) + hofs;
    f32x4 a0 = {}, a1 = {}, a2 = {}, a3 = {};
#pragma unroll
    for (int kk = 0; kk < 32; kk += 4) {
      u64x2 w0, w1, w2, w3;
      w0.x = __hip_atomic_load(hp + (kk + 0) * 8,     __ATOMIC_RELAXED, __HIP_MEMORY_SCOPE_AGENT);
      w0.y = __hip_atomic_load(hp + (kk + 0) * 8 + 1, __ATOMIC_RELAXED, __HIP_MEMORY_SCOPE_AGENT);
      w1.x = __hip_atomic_load(hp + (kk + 1) * 8,     __ATOMIC_RELAXED, __HIP_MEMORY_SCOPE_AGENT);
      w1.y = __hip_atomic_load(hp + (kk + 1) * 8 + 1, __ATOMIC_RELAXED, __HIP_MEMORY_SCOPE_AGENT);
      w2.x = __hip_atomic_load(hp + (kk + 2) * 8,     __ATOMIC_RELAXED, __HIP_MEMORY_SCOPE_AGENT);
      w2.y = __hip_atomic_load(hp + (kk + 2) * 8 + 1, __ATOMIC_RELAXED, __HIP_MEMORY_SCOPE_AGENT);
      w3.x = __hip_atomic_load(hp + (kk + 3) * 8,     __ATOMIC_RELAXED, __HIP_MEMORY_SCOPE_AGENT);
      w3.y = __hip_atomic_load(hp + (kk + 3) * 8 + 1, __ATOMIC_RELAXED, __HIP_MEMORY_SCOPE_AGENT);
      short8 av0 = __builtin_bit_cast(short8, w0);
      short8 av1 = __builtin_bit_cast(short8, w1);
      short8 av2 = __builtin_bit_cast(short8, w2);
      short8 av3 = __builtin_bit_cast(short8, w3);
      short8 bv0 = *reinterpret_cast<const short8*>(ldsb + ((lbase + (kk + 0) * 64) ^ sw));
      short8 bv1 = *reinterpret_cast<const short8*>(ldsb + ((lbase + (kk + 1) * 64) ^ sw));
      short8 bv2 = *reinterpret_cast<const short8*>(ldsb + ((lbase + (kk + 2) * 64) ^ sw));
      short8 bv3 = *reinterpret_cast<const short8*>(ldsb + ((lbase + (kk + 3) * 64) ^ sw));
      a0 = __builtin_amdgcn_mfma_f32_16x16x32_bf16(av0, bv0, a0, 0, 0, 0);
      a1 = __builtin_amdgcn_mfma_f32_16x16x32_bf16(av1, bv1, a1, 0, 0, 0);
      a2 = __builtin_amdgcn_mfma_f32_16x16x32_bf16(av2, bv2, a2, 0, 0, 0);
      a3 = __builtin_amdgcn_mfma_f32_16x16x32_bf16(av3, bv3, a3, 0, 0, 0);
    }
    f32x4 acc = (a0 + a1) + (a2 + a3);

#pragma unroll
    for (int j = 0; j < 4; ++j) {
      int batch = ((lane >> 4) << 2) + j;
      gates[g][batch][lane & 15] = acc[j] + xv[j] + bhv;
    }
    __syncthreads();

    float i_ = gates[0][eb][ec], f_ = gates[1][eb][ec];
    float g_ = gates[2][eb][ec], o_ = gates[3][eb][ec];
    i_ = 1.f / (1.f + __expf(-i_));
    f_ = 1.f / (1.f + __expf(-f_));
    g_ = tanhf(g_);
    o_ = 1.f / (1.f + __expf(-o_));
    float cn = f_ * creg + i_ * g_;
    creg = cn;
    u16 hbf = f2bf(o_ * tanhf(cn));
    htile[eb][ec] = hbf;
    hap[(long)t * HID] = hbf;       // normal store; flushed at kernel end
    __syncthreads();                // htile visible to wave 0

    if (tid < 64) {                 // coherent 8B stores of the new h slice
      int b = tid >> 2, c4 = (tid & 3) * 4;
      u64 v = *reinterpret_cast<const u64*>(&htile[b][c4]);
      int dst = ((t & 1) ? 0 : buf1) + ((b * HID + col0 + c4) >> 2);
      __hip_atomic_store(&hb64[dst], v, __ATOMIC_RELAXED, __HIP_MEMORY_SCOPE_AGENT);
    }
    if (t + 1 < SEQ) gbar();
  }
}

extern "C" void kernel_launch(void* const* d_in, const int* in_sizes, int n_in,
                              void* d_out, int out_size, void* d_ws, size_t ws_size,
                              hipStream_t stream) {
  const int*   x      = (const int*)d_in[0];
  const float* emb    = (const float*)d_in[1];
  const float* W_ih   = (const float*)d_in[2];
  const float* W_hh   = (const float*)d_in[3];
  const float* b_ih   = (const float*)d_in[4];
  const float* b_hh   = (const float*)d_in[5];
  const float* head_W = (const float*)d_in[6];
  const float* head_b = (const float*)d_in[7];
  float* out = (float*)d_out;

  char* ws = (char*)d_ws;
  size_t off = 0;
  auto alloc = [&](size_t bytes) -> void* {
    void* p = ws + off;
    off += (bytes + 255) & ~(size_t)255;
    return p;
  };
  u16*      Aemb  = (u16*)alloc((size_t)MTOT * EMB * 2);
  u16*      Wih_b = (u16*)alloc((size_t)GDIM * EMB * 2);
  u16*      Whh_b = (u16*)alloc((size_t)GDIM * HID * 2);
  u16*      HW_b  = (u16*)alloc((size_t)VOCAB * HID * 2);
  float*    xg    = (float*)alloc((size_t)MTOT * GDIM * 4);   // time-major [T][B][4H]
  u16*      h_all = (u16*)alloc((size_t)MTOT * HID * 2);
  u16*      h_buf = (u16*)alloc((size_t)2 * BATCH * HID * 2);
  unsigned* bar   = (unsigned*)alloc(256);

  hipMemsetAsync(bar, 0, 4, stream);

  cvt_bf16_v4<<<1024, 256, 0, stream>>>(W_ih, Wih_b, (long)GDIM * EMB / 4);
  cvt_bf16_v4<<<1024, 256, 0, stream>>>(W_hh, Whh_b, (long)GDIM * HID / 4);
  cvt_bf16_v4<<<2048, 256, 0, stream>>>(head_W, HW_b, (long)VOCAB * HID / 4);
  embed_gather<<<MTOT, 128, 0, stream>>>(x, emb, Aemb);

  gemm_bt<1><<<dim3(GDIM / 128, MTOT / 128), 256, 0, stream>>>(
      Aemb, Wih_b, b_ih, xg, MTOT, GDIM, EMB);

  {
    const float* xgc = xg;
    const u16* whc = Whh_b;
    void* args[] = {(void*)&xgc, (void*)&whc, (void*)&b_hh,
                    (void*)&h_buf, (void*)&h_all, (void*)&bar};
    hipLaunchCooperativeKernel((const void*)lstm_persist, dim3(NBLK), dim3(256),
                               args, 0, stream);
  }

  gemm_bt<0><<<dim3(VOCAB / 128, MTOT / 128), 256, 0, stream>>>(
      h_all, HW_b, head_b, out, MTOT, VOCAB, HID);
}

// Round 4
// 1721.655 us; speedup vs baseline: 3.1479x; 1.6760x over previous
//
#include <hip/hip_runtime.h>
#include <hip/hip_bf16.h>
#include <cstdint>
#include <cstddef>

typedef __attribute__((ext_vector_type(8))) short short8;
typedef __attribute__((ext_vector_type(4))) float f32x4;
typedef __attribute__((ext_vector_type(4))) float f4;
typedef __attribute__((ext_vector_type(4))) short s4;
typedef __attribute__((ext_vector_type(2))) unsigned long long u64x2;
typedef unsigned short u16;
typedef unsigned long long u64;

#define VOCAB 32000
#define EMB   512
#define HID   1024
#define GDIM  4096   // 4*HID
#define BATCH 16
#define SEQ   256
#define MTOT  4096   // BATCH*SEQ
#define NBLK  64     // lstm blocks

static __device__ __forceinline__ u16 f2bf(float f) {
  unsigned u = __builtin_bit_cast(unsigned, f);
  u += 0x7fffu + ((u >> 16) & 1u);   // RNE
  return (u16)(u >> 16);
}

static __device__ __forceinline__ float fsig(float x) {
  return __builtin_amdgcn_rcpf(1.f + __expf(-x));
}
static __device__ __forceinline__ float ftanh(float x) {
  return 1.f - 2.f * __builtin_amdgcn_rcpf(1.f + __expf(2.f * x));
}

__global__ void cvt_bf16_v4(const float* __restrict__ in, u16* __restrict__ out, long n4) {
  long i = (long)blockIdx.x * blockDim.x + threadIdx.x;
  long stride = (long)gridDim.x * blockDim.x;
  for (; i < n4; i += stride) {
    f4 v = reinterpret_cast<const f4*>(in)[i];
    s4 o;
#pragma unroll
    for (int j = 0; j < 4; ++j) o[j] = (short)f2bf(v[j]);
    reinterpret_cast<s4*>(out)[i] = o;
  }
}

__global__ void embed_gather(const int* __restrict__ x, const float* __restrict__ emb,
                             u16* __restrict__ A) {
  int m = blockIdx.x;                 // m = b*SEQ + t
  long base = (long)x[m] * EMB;
  int e4 = threadIdx.x;               // 0..127, 4 elems each
  f4 v = reinterpret_cast<const f4*>(emb + base)[e4];
  s4 o;
#pragma unroll
  for (int j = 0; j < 4; ++j) o[j] = (short)f2bf(v[j]);
  reinterpret_cast<s4*>(A + (long)m * EMB)[e4] = o;
}

static __device__ __forceinline__ void gload_lds16(const void* g, void* l) {
  __builtin_amdgcn_global_load_lds(
      (const __attribute__((address_space(1))) void*)g,
      (__attribute__((address_space(3))) void*)l, 16, 0, 0);
}

// C = A[M][K] * B[N][K]^T + bias[N]. bf16 in, f32 out. 128x128 tile, BK=32,
// global_load_lds width-16 staging. TXG=1: output row remapped to t*BATCH+b.
template<int TXG>
__global__ __launch_bounds__(256) void gemm_bt(
    const u16* __restrict__ A, const u16* __restrict__ B,
    const float* __restrict__ bias, float* __restrict__ C,
    int M, int N, int K)
{
  __shared__ u16 As[128 * 32];
  __shared__ u16 Bs[128 * 32];
  int tid  = threadIdx.x;
  int lane = tid & 63;
  int wid  = tid >> 6;
  int m0 = blockIdx.y * 128, n0 = blockIdx.x * 128;
  int wm = (wid >> 1) * 64, wn = (wid & 1) * 64;
  f32x4 acc[4][4] = {};

  int c0 = wid * 128 + lane;
  int c1 = c0 + 64;
  const u16* ga0 = A + (long)(m0 + (c0 >> 2)) * K + (c0 & 3) * 8;
  const u16* ga1 = A + (long)(m0 + (c1 >> 2)) * K + (c1 & 3) * 8;
  const u16* gb0 = B + (long)(n0 + (c0 >> 2)) * K + (c0 & 3) * 8;
  const u16* gb1 = B + (long)(n0 + (c1 >> 2)) * K + (c1 & 3) * 8;
  u16* la0 = As + wid * 1024;
  u16* la1 = la0 + 512;
  u16* lb0 = Bs + wid * 1024;
  u16* lb1 = lb0 + 512;

  for (int kt = 0; kt < K; kt += 32) {
    __syncthreads();
    gload_lds16(ga0 + kt, la0);
    gload_lds16(ga1 + kt, la1);
    gload_lds16(gb0 + kt, lb0);
    gload_lds16(gb1 + kt, lb1);
    __syncthreads();
    short8 af[4], bf[4];
#pragma unroll
    for (int i = 0; i < 4; ++i) {
      af[i] = *reinterpret_cast<const short8*>(&As[(wm + i * 16 + (lane & 15)) * 32 + ((lane >> 4) << 3)]);
      bf[i] = *reinterpret_cast<const short8*>(&Bs[(wn + i * 16 + (lane & 15)) * 32 + ((lane >> 4) << 3)]);
    }
#pragma unroll
    for (int i = 0; i < 4; ++i)
#pragma unroll
      for (int j = 0; j < 4; ++j)
        acc[i][j] = __builtin_amdgcn_mfma_f32_16x16x32_bf16(af[i], bf[j], acc[i][j], 0, 0, 0);
  }

#pragma unroll
  for (int i = 0; i < 4; ++i) {
    int m = m0 + wm + i * 16 + ((lane >> 4) << 2);
#pragma unroll
    for (int j = 0; j < 4; ++j) {
      int n = n0 + wn + j * 16 + (lane & 15);
      float bv = bias[n];
#pragma unroll
      for (int jj = 0; jj < 4; ++jj) {
        int mm = m + jj;
        long row;
        if constexpr (TXG) {
          row = (long)(mm & (SEQ - 1)) * BATCH + (mm >> 8);  // t*B + b
        } else {
          row = mm;
        }
        C[row * N + n] = acc[i][j][jj] + bv;
      }
    }
  }
}

// Persistent LSTM, 64 blocks x 256 threads. W_hh slice (4 gates x 16 cols x
// 1024 K = 128 KiB) LDS-resident, XOR-swizzled. K-split: wave w covers
// k in [256w, 256w+256) for ALL 4 gates (A loaded once, 4 MFMAs reuse it);
// partials reduced via LDS. Cross-block h via agent-scope atomics.
// Barrier: per-block flag lines (no RMW) + block0 poll + single epoch word.
__global__ __launch_bounds__(256, 1) void lstm_persist(
    const float* __restrict__ xg, const u16* __restrict__ Whh,
    const float* __restrict__ b_hh, u16* __restrict__ h_buf,
    u16* __restrict__ h_all, unsigned* __restrict__ flags,
    unsigned* __restrict__ epoch)
{
  __shared__ u16 Wlds[4 * 16 * 1024] __attribute__((aligned(16)));  // 128 KiB
  __shared__ float part[4][4][16][17];   // [wave][gate][batch][col], padded
  __shared__ u16 htile[16][16];

  int tid = threadIdx.x;
  int w = tid >> 6, lane = tid & 63;
  int bid = blockIdx.x;
  int col0 = bid * 16;

  // ---- stage Whh slice into LDS once (swizzled) ----
  for (int idx = tid; idx < 64 * 128; idx += 256) {
    int rl = idx >> 7;          // local row 0..63 = gate*16 + col
    int ch = idx & 127;
    int gg = rl >> 4, cc = rl & 15;
    short8 v = *reinterpret_cast<const short8*>(
        Whh + ((long)(gg * HID + col0 + cc) * HID + ch * 8));
    unsigned byte = ((unsigned)rl << 11) | ((unsigned)ch << 4);
    byte ^= ((byte >> 11) & 7u) << 4;
    *reinterpret_cast<short8*>(reinterpret_cast<char*>(Wlds) + byte) = v;
  }

  int r  = lane & 15;                 // A row (batch) / B row (gate col)
  int ko = (lane >> 4) << 3;          // k-octet within 32-wide K step
  int k0 = w * 256;                   // wave's K slice
  char* ldsb = reinterpret_cast<char*>(Wlds);
  unsigned sw = ((unsigned)(r & 7)) << 4;
  unsigned base0 = ((unsigned)r << 11) | ((unsigned)(k0 + ko) << 1);

  u64* hb64 = reinterpret_cast<u64*>(h_buf);
  const int hbase = (r * HID + k0 + ko) >> 2;   // u64 units
  const int buf1  = (BATCH * HID) >> 2;

  int eb = tid >> 4, ec = tid & 15;   // elementwise thread = (batch, col)
  const float* xgp = xg + (long)eb * GDIM + col0 + ec;
  float bias4[4];
#pragma unroll
  for (int g = 0; g < 4; ++g) bias4[g] = b_hh[g * HID + col0 + ec];
  u16* hap = h_all + (long)eb * SEQ * HID + col0 + ec;
  float creg = 0.f;

  // h0 = 0 (wave 0 stores own col-slice, buffer 0)
  if (tid < 64) {
    int b = tid >> 2, c4 = (tid & 3) * 4;
    __hip_atomic_store(&hb64[(b * HID + col0 + c4) >> 2], (u64)0,
                       __ATOMIC_RELAXED, __HIP_MEMORY_SCOPE_AGENT);
  }
  // arrival(1): wave 0 drains stores, tid0 raises flag
  if (tid < 64) {
    asm volatile("s_waitcnt vmcnt(0)" ::: "memory");
    if (tid == 0)
      __hip_atomic_store(&flags[(unsigned)bid * 32], 1u,
                         __ATOMIC_RELAXED, __HIP_MEMORY_SCOPE_AGENT);
  }
  if (bid == 0 && tid < 64) {         // block0 wave0: detect + publish
    while (__hip_atomic_load(&flags[(unsigned)tid * 32],
                             __ATOMIC_RELAXED, __HIP_MEMORY_SCOPE_AGENT) < 1u)
      __builtin_amdgcn_s_sleep(1);
    if (tid == 0)
      __hip_atomic_store(epoch, 1u, __ATOMIC_RELAXED, __HIP_MEMORY_SCOPE_AGENT);
  }

  float xv[4];
#pragma unroll
  for (int g = 0; g < 4; ++g) xv[g] = xgp[g * HID];   // prefetch t=0

  if (tid == 0) {
    while (__hip_atomic_load(epoch, __ATOMIC_RELAXED, __HIP_MEMORY_SCOPE_AGENT) < 1u)
      __builtin_amdgcn_s_sleep(1);
  }
  __syncthreads();

  for (int t = 0; t < SEQ; ++t) {
    // ---- recurrent GEMM partials: wave w, k-slice, all 4 gates ----
    const u64* hp = hb64 + ((t & 1) ? buf1 : 0) + hbase;
    f32x4 a0 = {}, a1 = {}, a2 = {}, a3 = {};
#pragma unroll
    for (int kk = 0; kk < 8; ++kk) {
      u64x2 wa;
      wa.x = __hip_atomic_load(hp + kk * 8,     __ATOMIC_RELAXED, __HIP_MEMORY_SCOPE_AGENT);
      wa.y = __hip_atomic_load(hp + kk * 8 + 1, __ATOMIC_RELAXED, __HIP_MEMORY_SCOPE_AGENT);
      short8 av = __builtin_bit_cast(short8, wa);
      unsigned byt = base0 + (unsigned)(kk * 64);
      short8 b0 = *reinterpret_cast<const short8*>(ldsb + ((byt            ) ^ sw));
      short8 b1 = *reinterpret_cast<const short8*>(ldsb + ((byt + 1u*32768u) ^ sw));
      short8 b2 = *reinterpret_cast<const short8*>(ldsb + ((byt + 2u*32768u) ^ sw));
      short8 b3 = *reinterpret_cast<const short8*>(ldsb + ((byt + 3u*32768u) ^ sw));
      a0 = __builtin_amdgcn_mfma_f32_16x16x32_bf16(av, b0, a0, 0, 0, 0);
      a1 = __builtin_amdgcn_mfma_f32_16x16x32_bf16(av, b1, a1, 0, 0, 0);
      a2 = __builtin_amdgcn_mfma_f32_16x16x32_bf16(av, b2, a2, 0, 0, 0);
      a3 = __builtin_amdgcn_mfma_f32_16x16x32_bf16(av, b3, a3, 0, 0, 0);
    }
#pragma unroll
    for (int j = 0; j < 4; ++j) {
      int batch = ((lane >> 4) << 2) + j;
      part[w][0][batch][lane & 15] = a0[j];
      part[w][1][batch][lane & 15] = a1[j];
      part[w][2][batch][lane & 15] = a2[j];
      part[w][3][batch][lane & 15] = a3[j];
    }
    __syncthreads();                       // partials visible

    // ---- elementwise ----
    float pre[4];
#pragma unroll
    for (int g = 0; g < 4; ++g)
      pre[g] = part[0][g][eb][ec] + part[1][g][eb][ec] +
               part[2][g][eb][ec] + part[3][g][eb][ec] + xv[g] + bias4[g];
    float i_ = fsig(pre[0]);
    float f_ = fsig(pre[1]);
    float g_ = ftanh(pre[2]);
    float o_ = fsig(pre[3]);
    float cn = f_ * creg + i_ * g_;
    creg = cn;
    u16 hbf = f2bf(o_ * ftanh(cn));
    htile[eb][ec] = hbf;
    hap[(long)t * HID] = hbf;
    __syncthreads();                       // htile visible to wave 0

    if (t + 1 == SEQ) break;

    // ---- publish h(t+1) + arrival (wave 0 only) ----
    unsigned e = (unsigned)(t + 2);
    if (tid < 64) {
      int b = tid >> 2, c4 = (tid & 3) * 4;
      u64 v = *reinterpret_cast<const u64*>(&htile[b][c4]);
      int dst = ((t & 1) ? 0 : buf1) + ((b * HID + col0 + c4) >> 2);
      __hip_atomic_store(&hb64[dst], v, __ATOMIC_RELAXED, __HIP_MEMORY_SCOPE_AGENT);
      asm volatile("s_waitcnt vmcnt(0)" ::: "memory");
      if (tid == 0)
        __hip_atomic_store(&flags[(unsigned)bid * 32], e,
                           __ATOMIC_RELAXED, __HIP_MEMORY_SCOPE_AGENT);
    }
    if (bid == 0 && tid < 64) {
      while (__hip_atomic_load(&flags[(unsigned)tid * 32],
                               __ATOMIC_RELAXED, __HIP_MEMORY_SCOPE_AGENT) < e)
        __builtin_amdgcn_s_sleep(1);
      if (tid == 0)
        __hip_atomic_store(epoch, e, __ATOMIC_RELAXED, __HIP_MEMORY_SCOPE_AGENT);
    }

#pragma unroll
    for (int g = 0; g < 4; ++g)
      xv[g] = xgp[(long)(t + 1) * BATCH * GDIM + g * HID];   // prefetch next

    if (tid == 0) {
      while (__hip_atomic_load(epoch, __ATOMIC_RELAXED, __HIP_MEMORY_SCOPE_AGENT) < e)
        __builtin_amdgcn_s_sleep(1);
    }
    __syncthreads();
  }
}

extern "C" void kernel_launch(void* const* d_in, const int* in_sizes, int n_in,
                              void* d_out, int out_size, void* d_ws, size_t ws_size,
                              hipStream_t stream) {
  const int*   x      = (const int*)d_in[0];
  const float* emb    = (const float*)d_in[1];
  const float* W_ih   = (const float*)d_in[2];
  const float* W_hh   = (const float*)d_in[3];
  const float* b_ih   = (const float*)d_in[4];
  const float* b_hh   = (const float*)d_in[5];
  const float* head_W = (const float*)d_in[6];
  const float* head_b = (const float*)d_in[7];
  float* out = (float*)d_out;

  char* ws = (char*)d_ws;
  size_t off = 0;
  auto alloc = [&](size_t bytes) -> void* {
    void* p = ws + off;
    off += (bytes + 255) & ~(size_t)255;
    return p;
  };
  u16*      Aemb  = (u16*)alloc((size_t)MTOT * EMB * 2);
  u16*      Wih_b = (u16*)alloc((size_t)GDIM * EMB * 2);
  u16*      Whh_b = (u16*)alloc((size_t)GDIM * HID * 2);
  u16*      HW_b  = (u16*)alloc((size_t)VOCAB * HID * 2);
  float*    xg    = (float*)alloc((size_t)MTOT * GDIM * 4);   // time-major [T][B][4H]
  u16*      h_all = (u16*)alloc((size_t)MTOT * HID * 2);
  u16*      h_buf = (u16*)alloc((size_t)2 * BATCH * HID * 2);
  unsigned* barmem= (unsigned*)alloc(16384);                  // flags[64*32] + epoch
  unsigned* flags = barmem;
  unsigned* epoch = barmem + 4096;                            // byte offset 16K? no: 4096*4=16KB region end
  // keep epoch inside the 16 KiB region: place at word 2048 (byte 8192)
  epoch = barmem + 2048;

  hipMemsetAsync(barmem, 0, 16384, stream);

  cvt_bf16_v4<<<1024, 256, 0, stream>>>(W_ih, Wih_b, (long)GDIM * EMB / 4);
  cvt_bf16_v4<<<1024, 256, 0, stream>>>(W_hh, Whh_b, (long)GDIM * HID / 4);
  cvt_bf16_v4<<<2048, 256, 0, stream>>>(head_W, HW_b, (long)VOCAB * HID / 4);
  embed_gather<<<MTOT, 128, 0, stream>>>(x, emb, Aemb);

  gemm_bt<1><<<dim3(GDIM / 128, MTOT / 128), 256, 0, stream>>>(
      Aemb, Wih_b, b_ih, xg, MTOT, GDIM, EMB);

  {
    const float* xgc = xg;
    const u16* whc = Whh_b;
    void* args[] = {(void*)&xgc, (void*)&whc, (void*)&b_hh,
                    (void*)&h_buf, (void*)&h_all, (void*)&flags, (void*)&epoch};
    hipLaunchCooperativeKernel((const void*)lstm_persist, dim3(NBLK), dim3(256),
                               args, 0, stream);
  }

  gemm_bt<0><<<dim3(VOCAB / 128, MTOT / 128), 256, 0, stream>>>(
      h_all, HW_b, head_b, out, MTOT, VOCAB, HID);
}

// Round 5
// 1626.648 us; speedup vs baseline: 3.3317x; 1.0584x over previous
//
#include <hip/hip_runtime.h>
#include <hip/hip_bf16.h>
#include <cstdint>
#include <cstddef>

typedef __attribute__((ext_vector_type(8))) short short8;
typedef __attribute__((ext_vector_type(4))) float f32x4;
typedef __attribute__((ext_vector_type(4))) float f4;
typedef __attribute__((ext_vector_type(4))) short s4;
typedef __attribute__((ext_vector_type(2))) unsigned long long u64x2;
typedef unsigned short u16;
typedef unsigned long long u64;

#define VOCAB 32000
#define EMB   512
#define HID   1024
#define GDIM  4096   // 4*HID
#define BATCH 16
#define SEQ   256
#define MTOT  4096   // BATCH*SEQ
#define NBLK  64     // lstm blocks

static __device__ __forceinline__ u16 f2bf(float f) {
  unsigned u = __builtin_bit_cast(unsigned, f);
  u += 0x7fffu + ((u >> 16) & 1u);   // RNE
  return (u16)(u >> 16);
}

static __device__ __forceinline__ float fsig(float x) {
  return __builtin_amdgcn_rcpf(1.f + __expf(-x));
}
static __device__ __forceinline__ float ftanh(float x) {
  return 1.f - 2.f * __builtin_amdgcn_rcpf(1.f + __expf(2.f * x));
}

__global__ void cvt_bf16_v4(const float* __restrict__ in, u16* __restrict__ out, long n4) {
  long i = (long)blockIdx.x * blockDim.x + threadIdx.x;
  long stride = (long)gridDim.x * blockDim.x;
  for (; i < n4; i += stride) {
    f4 v = reinterpret_cast<const f4*>(in)[i];
    s4 o;
#pragma unroll
    for (int j = 0; j < 4; ++j) o[j] = (short)f2bf(v[j]);
    reinterpret_cast<s4*>(out)[i] = o;
  }
}

__global__ void embed_gather(const int* __restrict__ x, const float* __restrict__ emb,
                             u16* __restrict__ A) {
  int m = blockIdx.x;                 // m = b*SEQ + t
  long base = (long)x[m] * EMB;
  int e4 = threadIdx.x;               // 0..127, 4 elems each
  f4 v = reinterpret_cast<const f4*>(emb + base)[e4];
  s4 o;
#pragma unroll
  for (int j = 0; j < 4; ++j) o[j] = (short)f2bf(v[j]);
  reinterpret_cast<s4*>(A + (long)m * EMB)[e4] = o;
}

static __device__ __forceinline__ void gload_lds16(const void* g, void* l) {
  __builtin_amdgcn_global_load_lds(
      (const __attribute__((address_space(1))) void*)g,
      (__attribute__((address_space(3))) void*)l, 16, 0, 0);
}

// C = A[M][K] * B[N][K]^T + bias[N]. bf16 in, f32 out. 128x128 tile, BK=32,
// global_load_lds width-16 staging. TXG=1: output row remapped to t*BATCH+b.
template<int TXG>
__global__ __launch_bounds__(256) void gemm_bt(
    const u16* __restrict__ A, const u16* __restrict__ B,
    const float* __restrict__ bias, float* __restrict__ C,
    int M, int N, int K)
{
  __shared__ u16 As[128 * 32];
  __shared__ u16 Bs[128 * 32];
  int tid  = threadIdx.x;
  int lane = tid & 63;
  int wid  = tid >> 6;
  int m0 = blockIdx.y * 128, n0 = blockIdx.x * 128;
  int wm = (wid >> 1) * 64, wn = (wid & 1) * 64;
  f32x4 acc[4][4] = {};

  int c0 = wid * 128 + lane;
  int c1 = c0 + 64;
  const u16* ga0 = A + (long)(m0 + (c0 >> 2)) * K + (c0 & 3) * 8;
  const u16* ga1 = A + (long)(m0 + (c1 >> 2)) * K + (c1 & 3) * 8;
  const u16* gb0 = B + (long)(n0 + (c0 >> 2)) * K + (c0 & 3) * 8;
  const u16* gb1 = B + (long)(n0 + (c1 >> 2)) * K + (c1 & 3) * 8;
  u16* la0 = As + wid * 1024;
  u16* la1 = la0 + 512;
  u16* lb0 = Bs + wid * 1024;
  u16* lb1 = lb0 + 512;

  for (int kt = 0; kt < K; kt += 32) {
    __syncthreads();
    gload_lds16(ga0 + kt, la0);
    gload_lds16(ga1 + kt, la1);
    gload_lds16(gb0 + kt, lb0);
    gload_lds16(gb1 + kt, lb1);
    __syncthreads();
    short8 af[4], bf[4];
#pragma unroll
    for (int i = 0; i < 4; ++i) {
      af[i] = *reinterpret_cast<const short8*>(&As[(wm + i * 16 + (lane & 15)) * 32 + ((lane >> 4) << 3)]);
      bf[i] = *reinterpret_cast<const short8*>(&Bs[(wn + i * 16 + (lane & 15)) * 32 + ((lane >> 4) << 3)]);
    }
#pragma unroll
    for (int i = 0; i < 4; ++i)
#pragma unroll
      for (int j = 0; j < 4; ++j)
        acc[i][j] = __builtin_amdgcn_mfma_f32_16x16x32_bf16(af[i], bf[j], acc[i][j], 0, 0, 0);
  }

#pragma unroll
  for (int i = 0; i < 4; ++i) {
    int m = m0 + wm + i * 16 + ((lane >> 4) << 2);
#pragma unroll
    for (int j = 0; j < 4; ++j) {
      int n = n0 + wn + j * 16 + (lane & 15);
      float bv = bias[n];
#pragma unroll
      for (int jj = 0; jj < 4; ++jj) {
        int mm = m + jj;
        long row;
        if constexpr (TXG) {
          row = (long)(mm & (SEQ - 1)) * BATCH + (mm >> 8);  // t*B + b
        } else {
          row = mm;
        }
        C[row * N + n] = acc[i][j][jj] + bv;
      }
    }
  }
}

// Persistent LSTM, 64 blocks x 256 threads. W_hh slice (128 KiB) LDS-resident,
// XOR-swizzled. Wave w covers k in [256w,256w+256) for all 4 gates.
// h slab layout: [2 bufs][64 producers][16 batch][16 col] u16 (contig/producer).
// Distributed sync: wave w polls ONLY its 16 producers' flags; the block-wide
// __syncthreads before elementwise certifies all-64-published, preserving the
// double-buffer WAR invariant. No aggregator, no epoch.
__global__ __launch_bounds__(256, 1) void lstm_persist(
    const float* __restrict__ xg, const u16* __restrict__ Whh,
    const float* __restrict__ b_hh, u16* __restrict__ h_buf,
    u16* __restrict__ h_all, unsigned* __restrict__ flags)
{
  __shared__ u16 Wlds[4 * 16 * 1024] __attribute__((aligned(16)));  // 128 KiB
  __shared__ float part[4][4][16][17];   // [wave][gate][batch][col], padded
  __shared__ u16 htile[16][16];

  int tid = threadIdx.x;
  int w = tid >> 6, lane = tid & 63;
  int bid = blockIdx.x;
  int col0 = bid * 16;

  // ---- stage Whh slice into LDS once (swizzled) ----
  for (int idx = tid; idx < 64 * 128; idx += 256) {
    int rl = idx >> 7;          // local row 0..63 = gate*16 + col
    int ch = idx & 127;
    int gg = rl >> 4, cc = rl & 15;
    short8 v = *reinterpret_cast<const short8*>(
        Whh + ((long)(gg * HID + col0 + cc) * HID + ch * 8));
    unsigned byte = ((unsigned)rl << 11) | ((unsigned)ch << 4);
    byte ^= ((byte >> 11) & 7u) << 4;
    *reinterpret_cast<short8*>(reinterpret_cast<char*>(Wlds) + byte) = v;
  }

  int r  = lane & 15;                 // A row (batch) / B row (gate col)
  int ko = (lane >> 4) << 3;          // k-octet within 32-wide K step
  char* ldsb = reinterpret_cast<char*>(Wlds);
  unsigned sw = ((unsigned)(r & 7)) << 4;
  unsigned base0 = ((unsigned)r << 11) | ((unsigned)(w * 256 + ko) << 1);

  u64* hb64 = reinterpret_cast<u64*>(h_buf);
  // consumer u64 index within a buffer: wave w, lane (r, ko)
  const int hbase = (w * 4096 + ((ko >> 4) << 8) + (r << 4) + (ko & 8)) >> 2;
  const int BUFW = 4096;              // u64 words per buffer (64*256 u16 / 4)

  // this wave's 16 producers (lane i polls producer 16w + (i&15))
  const unsigned* myflag = flags + (unsigned)((w << 4) + (lane & 15)) * 32;

  int eb = tid >> 4, ec = tid & 15;   // elementwise thread = (batch, col)
  const float* xgp = xg + (long)eb * GDIM + col0 + ec;
  float bias4[4];
#pragma unroll
  for (int g = 0; g < 4; ++g) bias4[g] = b_hh[g * HID + col0 + ec];
  u16* hap = h_all + (long)eb * SEQ * HID + col0 + ec;
  float creg = 0.f;

  // ---- publish h(0)=0 : wave 0 lane l -> u64 word bid*64+l of buf0 ----
  if (tid < 64) {
    __hip_atomic_store(&hb64[bid * 64 + tid], (u64)0,
                       __ATOMIC_RELAXED, __HIP_MEMORY_SCOPE_AGENT);
    asm volatile("s_waitcnt vmcnt(0)" ::: "memory");
    if (tid == 0)
      __hip_atomic_store(&flags[(unsigned)bid * 32], 1u,
                         __ATOMIC_RELAXED, __HIP_MEMORY_SCOPE_AGENT);
  }

  float xv[4];
#pragma unroll
  for (int g = 0; g < 4; ++g) xv[g] = xgp[g * HID];   // prefetch t=0

  for (int t = 0; t < SEQ; ++t) {
    // ---- distributed poll: this wave's 16 producers published h(t)? ----
    unsigned want = (unsigned)(t + 1);
    while (__hip_atomic_load(myflag, __ATOMIC_RELAXED, __HIP_MEMORY_SCOPE_AGENT) < want) {}
    asm volatile("" ::: "memory");

    // ---- recurrent GEMM partials: wave w, k-slice, all 4 gates ----
    const u64* hp = hb64 + (t & 1) * BUFW + hbase;
    f32x4 a0 = {}, a1 = {}, a2 = {}, a3 = {};
#pragma unroll
    for (int kk = 0; kk < 8; ++kk) {
      u64x2 wa;
      wa.x = __hip_atomic_load(hp + kk * 128,     __ATOMIC_RELAXED, __HIP_MEMORY_SCOPE_AGENT);
      wa.y = __hip_atomic_load(hp + kk * 128 + 1, __ATOMIC_RELAXED, __HIP_MEMORY_SCOPE_AGENT);
      short8 av = __builtin_bit_cast(short8, wa);
      unsigned byt = base0 + (unsigned)(kk * 64);
      short8 b0 = *reinterpret_cast<const short8*>(ldsb + ((byt            ) ^ sw));
      short8 b1 = *reinterpret_cast<const short8*>(ldsb + ((byt + 1u*32768u) ^ sw));
      short8 b2 = *reinterpret_cast<const short8*>(ldsb + ((byt + 2u*32768u) ^ sw));
      short8 b3 = *reinterpret_cast<const short8*>(ldsb + ((byt + 3u*32768u) ^ sw));
      a0 = __builtin_amdgcn_mfma_f32_16x16x32_bf16(av, b0, a0, 0, 0, 0);
      a1 = __builtin_amdgcn_mfma_f32_16x16x32_bf16(av, b1, a1, 0, 0, 0);
      a2 = __builtin_amdgcn_mfma_f32_16x16x32_bf16(av, b2, a2, 0, 0, 0);
      a3 = __builtin_amdgcn_mfma_f32_16x16x32_bf16(av, b3, a3, 0, 0, 0);
    }
#pragma unroll
    for (int j = 0; j < 4; ++j) {
      int batch = ((lane >> 4) << 2) + j;
      part[w][0][batch][lane & 15] = a0[j];
      part[w][1][batch][lane & 15] = a1[j];
      part[w][2][batch][lane & 15] = a2[j];
      part[w][3][batch][lane & 15] = a3[j];
    }
    __syncthreads();                       // (A) partials visible; certifies
                                           // all 64 producers published h(t)
    // ---- elementwise ----
    float pre[4];
#pragma unroll
    for (int g = 0; g < 4; ++g)
      pre[g] = part[0][g][eb][ec] + part[1][g][eb][ec] +
               part[2][g][eb][ec] + part[3][g][eb][ec] + xv[g] + bias4[g];
    float i_ = fsig(pre[0]);
    float f_ = fsig(pre[1]);
    float g_ = ftanh(pre[2]);
    float o_ = fsig(pre[3]);
    float cn = f_ * creg + i_ * g_;
    creg = cn;
    u16 hbf = f2bf(o_ * ftanh(cn));
    htile[eb][ec] = hbf;
    __syncthreads();                       // (B) htile visible to wave 0

    // ---- publish h(t+1) + flag (wave 0, critical path first) ----
    if (t + 1 < SEQ && tid < 64) {
      u64 v = *reinterpret_cast<const u64*>(&htile[tid >> 2][(tid & 3) * 4]);
      __hip_atomic_store(&hb64[((t + 1) & 1) * BUFW + bid * 64 + tid], v,
                         __ATOMIC_RELAXED, __HIP_MEMORY_SCOPE_AGENT);
      asm volatile("s_waitcnt vmcnt(0)" ::: "memory");
      if (tid == 0)
        __hip_atomic_store(&flags[(unsigned)bid * 32], (unsigned)(t + 2),
                           __ATOMIC_RELAXED, __HIP_MEMORY_SCOPE_AGENT);
    }

    // ---- off-critical-path: h_all store + next xg prefetch ----
    hap[(long)t * HID] = hbf;
    int tn = (t + 1 < SEQ) ? t + 1 : t;
#pragma unroll
    for (int g = 0; g < 4; ++g)
      xv[g] = xgp[(long)tn * BATCH * GDIM + g * HID];
  }
}

extern "C" void kernel_launch(void* const* d_in, const int* in_sizes, int n_in,
                              void* d_out, int out_size, void* d_ws, size_t ws_size,
                              hipStream_t stream) {
  const int*   x      = (const int*)d_in[0];
  const float* emb    = (const float*)d_in[1];
  const float* W_ih   = (const float*)d_in[2];
  const float* W_hh   = (const float*)d_in[3];
  const float* b_ih   = (const float*)d_in[4];
  const float* b_hh   = (const float*)d_in[5];
  const float* head_W = (const float*)d_in[6];
  const float* head_b = (const float*)d_in[7];
  float* out = (float*)d_out;

  char* ws = (char*)d_ws;
  size_t off = 0;
  auto alloc = [&](size_t bytes) -> void* {
    void* p = ws + off;
    off += (bytes + 255) & ~(size_t)255;
    return p;
  };
  u16*      Aemb  = (u16*)alloc((size_t)MTOT * EMB * 2);
  u16*      Wih_b = (u16*)alloc((size_t)GDIM * EMB * 2);
  u16*      Whh_b = (u16*)alloc((size_t)GDIM * HID * 2);
  u16*      HW_b  = (u16*)alloc((size_t)VOCAB * HID * 2);
  float*    xg    = (float*)alloc((size_t)MTOT * GDIM * 4);   // time-major [T][B][4H]
  u16*      h_all = (u16*)alloc((size_t)MTOT * HID * 2);
  u16*      h_buf = (u16*)alloc((size_t)2 * NBLK * 256 * 2);  // [2][64][16][16] u16
  unsigned* flags = (unsigned*)alloc(8192);                   // 64 x 128B lines

  hipMemsetAsync(flags, 0, 8192, stream);

  cvt_bf16_v4<<<1024, 256, 0, stream>>>(W_ih, Wih_b, (long)GDIM * EMB / 4);
  cvt_bf16_v4<<<1024, 256, 0, stream>>>(W_hh, Whh_b, (long)GDIM * HID / 4);
  cvt_bf16_v4<<<2048, 256, 0, stream>>>(head_W, HW_b, (long)VOCAB * HID / 4);
  embed_gather<<<MTOT, 128, 0, stream>>>(x, emb, Aemb);

  gemm_bt<1><<<dim3(GDIM / 128, MTOT / 128), 256, 0, stream>>>(
      Aemb, Wih_b, b_ih, xg, MTOT, GDIM, EMB);

  {
    const float* xgc = xg;
    const u16* whc = Whh_b;
    void* args[] = {(void*)&xgc, (void*)&whc, (void*)&b_hh,
                    (void*)&h_buf, (void*)&h_all, (void*)&flags};
    hipLaunchCooperativeKernel((const void*)lstm_persist, dim3(NBLK), dim3(256),
                               args, 0, stream);
  }

  gemm_bt<0><<<dim3(VOCAB / 128, MTOT / 128), 256, 0, stream>>>(
      h_all, HW_b, head_b, out, MTOT, VOCAB, HID);
}

// Round 6
// 1609.541 us; speedup vs baseline: 3.3671x; 1.0106x over previous
//
#include <hip/hip_runtime.h>
#include <hip/hip_bf16.h>
#include <cstdint>
#include <cstddef>

typedef __attribute__((ext_vector_type(8))) short short8;
typedef __attribute__((ext_vector_type(4))) float f32x4;
typedef __attribute__((ext_vector_type(4))) float f4;
typedef __attribute__((ext_vector_type(4))) short s4;
typedef __attribute__((ext_vector_type(4))) unsigned u32x4;
typedef unsigned short u16;
typedef unsigned long long u64;

#define VOCAB 32000
#define EMB   512
#define HID   1024
#define GDIM  4096   // 4*HID
#define BATCH 16
#define SEQ   256
#define MTOT  4096   // BATCH*SEQ
#define NBLK  64     // lstm blocks

static __device__ __forceinline__ u16 f2bf(float f) {
  unsigned u = __builtin_bit_cast(unsigned, f);
  u += 0x7fffu + ((u >> 16) & 1u);   // RNE
  return (u16)(u >> 16);
}

static __device__ __forceinline__ float fsig(float x) {
  return __builtin_amdgcn_rcpf(1.f + __expf(-x));
}
static __device__ __forceinline__ float ftanh(float x) {
  return 1.f - 2.f * __builtin_amdgcn_rcpf(1.f + __expf(2.f * x));
}

__global__ void cvt_bf16_v4(const float* __restrict__ in, u16* __restrict__ out, long n4) {
  long i = (long)blockIdx.x * blockDim.x + threadIdx.x;
  long stride = (long)gridDim.x * blockDim.x;
  for (; i < n4; i += stride) {
    f4 v = reinterpret_cast<const f4*>(in)[i];
    s4 o;
#pragma unroll
    for (int j = 0; j < 4; ++j) o[j] = (short)f2bf(v[j]);
    reinterpret_cast<s4*>(out)[i] = o;
  }
}

__global__ void embed_gather(const int* __restrict__ x, const float* __restrict__ emb,
                             u16* __restrict__ A) {
  int m = blockIdx.x;                 // m = b*SEQ + t
  long base = (long)x[m] * EMB;
  int e4 = threadIdx.x;               // 0..127, 4 elems each
  f4 v = reinterpret_cast<const f4*>(emb + base)[e4];
  s4 o;
#pragma unroll
  for (int j = 0; j < 4; ++j) o[j] = (short)f2bf(v[j]);
  reinterpret_cast<s4*>(A + (long)m * EMB)[e4] = o;
}

static __device__ __forceinline__ void gload_lds16(const void* g, void* l) {
  __builtin_amdgcn_global_load_lds(
      (const __attribute__((address_space(1))) void*)g,
      (__attribute__((address_space(3))) void*)l, 16, 0, 0);
}

// C = A[M][K] * B[N][K]^T + bias[N]. bf16 in, f32 out. 128x128 tile, BK=32,
// global_load_lds width-16 staging. TXG=1: output row remapped to t*BATCH+b.
template<int TXG>
__global__ __launch_bounds__(256) void gemm_bt(
    const u16* __restrict__ A, const u16* __restrict__ B,
    const float* __restrict__ bias, float* __restrict__ C,
    int M, int N, int K)
{
  __shared__ u16 As[128 * 32];
  __shared__ u16 Bs[128 * 32];
  int tid  = threadIdx.x;
  int lane = tid & 63;
  int wid  = tid >> 6;
  int m0 = blockIdx.y * 128, n0 = blockIdx.x * 128;
  int wm = (wid >> 1) * 64, wn = (wid & 1) * 64;
  f32x4 acc[4][4] = {};

  int c0 = wid * 128 + lane;
  int c1 = c0 + 64;
  const u16* ga0 = A + (long)(m0 + (c0 >> 2)) * K + (c0 & 3) * 8;
  const u16* ga1 = A + (long)(m0 + (c1 >> 2)) * K + (c1 & 3) * 8;
  const u16* gb0 = B + (long)(n0 + (c0 >> 2)) * K + (c0 & 3) * 8;
  const u16* gb1 = B + (long)(n0 + (c1 >> 2)) * K + (c1 & 3) * 8;
  u16* la0 = As + wid * 1024;
  u16* la1 = la0 + 512;
  u16* lb0 = Bs + wid * 1024;
  u16* lb1 = lb0 + 512;

  for (int kt = 0; kt < K; kt += 32) {
    __syncthreads();
    gload_lds16(ga0 + kt, la0);
    gload_lds16(ga1 + kt, la1);
    gload_lds16(gb0 + kt, lb0);
    gload_lds16(gb1 + kt, lb1);
    __syncthreads();
    short8 af[4], bf[4];
#pragma unroll
    for (int i = 0; i < 4; ++i) {
      af[i] = *reinterpret_cast<const short8*>(&As[(wm + i * 16 + (lane & 15)) * 32 + ((lane >> 4) << 3)]);
      bf[i] = *reinterpret_cast<const short8*>(&Bs[(wn + i * 16 + (lane & 15)) * 32 + ((lane >> 4) << 3)]);
    }
#pragma unroll
    for (int i = 0; i < 4; ++i)
#pragma unroll
      for (int j = 0; j < 4; ++j)
        acc[i][j] = __builtin_amdgcn_mfma_f32_16x16x32_bf16(af[i], bf[j], acc[i][j], 0, 0, 0);
  }

#pragma unroll
  for (int i = 0; i < 4; ++i) {
    int m = m0 + wm + i * 16 + ((lane >> 4) << 2);
#pragma unroll
    for (int j = 0; j < 4; ++j) {
      int n = n0 + wn + j * 16 + (lane & 15);
      float bv = bias[n];
#pragma unroll
      for (int jj = 0; jj < 4; ++jj) {
        int mm = m + jj;
        long row;
        if constexpr (TXG) {
          row = (long)(mm & (SEQ - 1)) * BATCH + (mm >> 8);  // t*B + b
        } else {
          row = mm;
        }
        C[row * N + n] = acc[i][j][jj] + bv;
      }
    }
  }
}

// Persistent LSTM, 64 blocks x 256 threads. W_hh slice (128 KiB) LDS-resident,
// XOR-swizzled. Wave w covers k in [256w,256w+256) for all 4 gates.
// h exchange: SELF-CERTIFYING tagged words. Thread (b,c) of block p stores
// u32 = h_bf16 | tag<<16 at h_buf[buf][p][b][c] (relaxed agent store, 4B
// atomicity guarantees (h,tag) consistency). Consumers bulk-poll their 32
// tagged u64s until all tags >= t+1 — the polling load IS the data load.
// No flags, no vmcnt drain, no producer-side gather. Double-buffer WAR safe:
// tag in buf[t&1] can only be t+1 (fresh) or t (stale from h(t-2)); h(t+2)
// can't land before every block passed sync(A)@t (which requires this
// consumer's own publish of h(t+1)).
__global__ __launch_bounds__(256, 1) void lstm_persist(
    const float* __restrict__ xg, const u16* __restrict__ Whh,
    const float* __restrict__ b_hh, unsigned* __restrict__ h_buf,
    u16* __restrict__ h_all)
{
  __shared__ u16 Wlds[4 * 16 * 1024] __attribute__((aligned(16)));  // 128 KiB
  __shared__ float part[4][4][16][17];   // [wave][gate][batch][col], padded

  int tid = threadIdx.x;
  int w = tid >> 6, lane = tid & 63;
  int bid = blockIdx.x;
  int col0 = bid * 16;

  // ---- stage Whh slice into LDS once (swizzled) ----
  for (int idx = tid; idx < 64 * 128; idx += 256) {
    int rl = idx >> 7;          // local row 0..63 = gate*16 + col
    int ch = idx & 127;
    int gg = rl >> 4, cc = rl & 15;
    short8 v = *reinterpret_cast<const short8*>(
        Whh + ((long)(gg * HID + col0 + cc) * HID + ch * 8));
    unsigned byte = ((unsigned)rl << 11) | ((unsigned)ch << 4);
    byte ^= ((byte >> 11) & 7u) << 4;
    *reinterpret_cast<short8*>(reinterpret_cast<char*>(Wlds) + byte) = v;
  }

  int r  = lane & 15;                 // A row (batch) / B row (gate col)
  int ko = (lane >> 4) << 3;          // k-octet within 32-wide K step
  char* ldsb = reinterpret_cast<char*>(Wlds);
  unsigned sw = ((unsigned)(r & 7)) << 4;
  unsigned base0 = ((unsigned)r << 11) | ((unsigned)(w * 256 + ko) << 1);

  const u64* hb64 = reinterpret_cast<const u64*>(h_buf);
  // consumer: per kk needs h[r][w*256+kk*32+ko .. +7] = 4 tagged u64
  // u64 index: p*128 + r*8 + (c>>1);  p = w*16 + kk*2 + (ko>>4), c = ko&8
  const int base_lane = w * 2048 + ((ko >> 4) << 7) + (r << 3) + ((ko & 8) >> 1);
  const int BUF64 = 8192;             // u64 words per buffer

  int eb = tid >> 4, ec = tid & 15;   // elementwise thread = (batch, col)
  const float* xgp = xg + (long)eb * GDIM + col0 + ec;
  float bias4[4];
#pragma unroll
  for (int g = 0; g < 4; ++g) bias4[g] = b_hh[g * HID + col0 + ec];
  u16* hap = h_all + (long)eb * SEQ * HID + col0 + ec;
  float creg = 0.f;

  // publish h(0)=0 with tag 1 into buf0 (this thread's own word)
  __hip_atomic_store(&h_buf[(bid << 8) + tid], 1u << 16,
                     __ATOMIC_RELAXED, __HIP_MEMORY_SCOPE_AGENT);

  float xv[4];
#pragma unroll
  for (int g = 0; g < 4; ++g) xv[g] = xgp[g * HID];   // prefetch t=0

  for (int t = 0; t < SEQ; ++t) {
    unsigned want = (unsigned)(t + 1);
    const u64* hp = hb64 + ((t & 1) ? BUF64 : 0) + base_lane;

    f32x4 a0 = {}, a1 = {}, a2 = {}, a3 = {};
#pragma unroll
    for (int ph = 0; ph < 2; ++ph) {
      u64 q[4][4];
      bool allok;
      do {
        allok = true;
#pragma unroll
        for (int kk = 0; kk < 4; ++kk)
#pragma unroll
          for (int j = 0; j < 4; ++j)
            q[kk][j] = __hip_atomic_load(hp + (ph * 4 + kk) * 256 + j,
                                         __ATOMIC_RELAXED, __HIP_MEMORY_SCOPE_AGENT);
#pragma unroll
        for (int kk = 0; kk < 4; ++kk)
#pragma unroll
          for (int j = 0; j < 4; ++j) {
            allok = allok && (((unsigned)(q[kk][j] >> 16) & 0xffffu) >= want);
            allok = allok && ((unsigned)(q[kk][j] >> 48) >= want);
          }
      } while (!__all(allok));

#pragma unroll
      for (int kk = 0; kk < 4; ++kk) {
        u32x4 wv;
#pragma unroll
        for (int j = 0; j < 4; ++j)
          wv[j] = ((unsigned)(q[kk][j] & 0xffffu)) |
                  ((unsigned)(q[kk][j] >> 16) & 0xffff0000u);
        short8 av = __builtin_bit_cast(short8, wv);
        unsigned byt = base0 + (unsigned)((ph * 4 + kk) * 64);
        short8 b0 = *reinterpret_cast<const short8*>(ldsb + ((byt            ) ^ sw));
        short8 b1 = *reinterpret_cast<const short8*>(ldsb + ((byt + 1u*32768u) ^ sw));
        short8 b2 = *reinterpret_cast<const short8*>(ldsb + ((byt + 2u*32768u) ^ sw));
        short8 b3 = *reinterpret_cast<const short8*>(ldsb + ((byt + 3u*32768u) ^ sw));
        a0 = __builtin_amdgcn_mfma_f32_16x16x32_bf16(av, b0, a0, 0, 0, 0);
        a1 = __builtin_amdgcn_mfma_f32_16x16x32_bf16(av, b1, a1, 0, 0, 0);
        a2 = __builtin_amdgcn_mfma_f32_16x16x32_bf16(av, b2, a2, 0, 0, 0);
        a3 = __builtin_amdgcn_mfma_f32_16x16x32_bf16(av, b3, a3, 0, 0, 0);
      }
    }

#pragma unroll
    for (int j = 0; j < 4; ++j) {
      int batch = ((lane >> 4) << 2) + j;
      part[w][0][batch][lane & 15] = a0[j];
      part[w][1][batch][lane & 15] = a1[j];
      part[w][2][batch][lane & 15] = a2[j];
      part[w][3][batch][lane & 15] = a3[j];
    }
    __syncthreads();                       // (A) partials visible; also
                                           // certifies all h(t) tags were seen
    // ---- elementwise ----
    float pre[4];
#pragma unroll
    for (int g = 0; g < 4; ++g)
      pre[g] = part[0][g][eb][ec] + part[1][g][eb][ec] +
               part[2][g][eb][ec] + part[3][g][eb][ec] + xv[g] + bias4[g];
    float i_ = fsig(pre[0]);
    float f_ = fsig(pre[1]);
    float g_ = ftanh(pre[2]);
    float o_ = fsig(pre[3]);
    float cn = f_ * creg + i_ * g_;
    creg = cn;
    u16 hbf = f2bf(o_ * ftanh(cn));

    // ---- publish h(t+1): one self-tagged u32, fire-and-forget ----
    if (t + 1 < SEQ) {
      unsigned word = (unsigned)hbf | ((unsigned)(t + 2) << 16);
      __hip_atomic_store(&h_buf[(((t + 1) & 1) << 14) + (bid << 8) + tid], word,
                         __ATOMIC_RELAXED, __HIP_MEMORY_SCOPE_AGENT);
    }

    // ---- off-critical-path: h_all store + next xg prefetch ----
    hap[(long)t * HID] = hbf;
    int tn = (t + 1 < SEQ) ? t + 1 : t;
#pragma unroll
    for (int g = 0; g < 4; ++g)
      xv[g] = xgp[(long)tn * BATCH * GDIM + g * HID];

    __syncthreads();                       // keep waves step-aligned
  }
}

extern "C" void kernel_launch(void* const* d_in, const int* in_sizes, int n_in,
                              void* d_out, int out_size, void* d_ws, size_t ws_size,
                              hipStream_t stream) {
  const int*   x      = (const int*)d_in[0];
  const float* emb    = (const float*)d_in[1];
  const float* W_ih   = (const float*)d_in[2];
  const float* W_hh   = (const float*)d_in[3];
  const float* b_ih   = (const float*)d_in[4];
  const float* b_hh   = (const float*)d_in[5];
  const float* head_W = (const float*)d_in[6];
  const float* head_b = (const float*)d_in[7];
  float* out = (float*)d_out;

  char* ws = (char*)d_ws;
  size_t off = 0;
  auto alloc = [&](size_t bytes) -> void* {
    void* p = ws + off;
    off += (bytes + 255) & ~(size_t)255;
    return p;
  };
  u16*      Aemb  = (u16*)alloc((size_t)MTOT * EMB * 2);
  u16*      Wih_b = (u16*)alloc((size_t)GDIM * EMB * 2);
  u16*      Whh_b = (u16*)alloc((size_t)GDIM * HID * 2);
  u16*      HW_b  = (u16*)alloc((size_t)VOCAB * HID * 2);
  float*    xg    = (float*)alloc((size_t)MTOT * GDIM * 4);   // time-major [T][B][4H]
  u16*      h_all = (u16*)alloc((size_t)MTOT * HID * 2);
  unsigned* h_buf = (unsigned*)alloc((size_t)2 * NBLK * 256 * 4); // [2][64][16][16] tagged u32

  // zero tags (harness poisons ws with 0xAA -> would fake tags otherwise)
  hipMemsetAsync(h_buf, 0, (size_t)2 * NBLK * 256 * 4, stream);

  cvt_bf16_v4<<<1024, 256, 0, stream>>>(W_ih, Wih_b, (long)GDIM * EMB / 4);
  cvt_bf16_v4<<<1024, 256, 0, stream>>>(W_hh, Whh_b, (long)GDIM * HID / 4);
  cvt_bf16_v4<<<2048, 256, 0, stream>>>(head_W, HW_b, (long)VOCAB * HID / 4);
  embed_gather<<<MTOT, 128, 0, stream>>>(x, emb, Aemb);

  gemm_bt<1><<<dim3(GDIM / 128, MTOT / 128), 256, 0, stream>>>(
      Aemb, Wih_b, b_ih, xg, MTOT, GDIM, EMB);

  {
    const float* xgc = xg;
    const u16* whc = Whh_b;
    void* args[] = {(void*)&xgc, (void*)&whc, (void*)&b_hh,
                    (void*)&h_buf, (void*)&h_all};
    hipLaunchCooperativeKernel((const void*)lstm_persist, dim3(NBLK), dim3(256),
                               args, 0, stream);
  }

  gemm_bt<0><<<dim3(VOCAB / 128, MTOT / 128), 256, 0, stream>>>(
      h_all, HW_b, head_b, out, MTOT, VOCAB, HID);
}

// Round 7
// 1504.908 us; speedup vs baseline: 3.6013x; 1.0695x over previous
//
#include <hip/hip_runtime.h>
#include <hip/hip_bf16.h>
#include <cstdint>
#include <cstddef>

typedef __attribute__((ext_vector_type(8))) short short8;
typedef __attribute__((ext_vector_type(4))) float f32x4;
typedef __attribute__((ext_vector_type(4))) float f4;
typedef __attribute__((ext_vector_type(4))) short s4;
typedef __attribute__((ext_vector_type(4))) unsigned u32x4;
typedef unsigned short u16;
typedef unsigned long long u64;

#define VOCAB 32000
#define EMB   512
#define HID   1024
#define GDIM  4096   // 4*HID
#define BATCH 16
#define SEQ   256
#define MTOT  4096   // BATCH*SEQ
#define NBLK  64     // lstm blocks

static __device__ __forceinline__ u16 f2bf(float f) {
  unsigned u = __builtin_bit_cast(unsigned, f);
  u += 0x7fffu + ((u >> 16) & 1u);   // RNE
  return (u16)(u >> 16);
}

static __device__ __forceinline__ float fsig(float x) {
  return __builtin_amdgcn_rcpf(1.f + __expf(-x));
}
static __device__ __forceinline__ float ftanh(float x) {
  return 1.f - 2.f * __builtin_amdgcn_rcpf(1.f + __expf(2.f * x));
}

__global__ void cvt_bf16_v4(const float* __restrict__ in, u16* __restrict__ out, long n4) {
  long i = (long)blockIdx.x * blockDim.x + threadIdx.x;
  long stride = (long)gridDim.x * blockDim.x;
  for (; i < n4; i += stride) {
    f4 v = reinterpret_cast<const f4*>(in)[i];
    s4 o;
#pragma unroll
    for (int j = 0; j < 4; ++j) o[j] = (short)f2bf(v[j]);
    reinterpret_cast<s4*>(out)[i] = o;
  }
}

__global__ void embed_gather(const int* __restrict__ x, const float* __restrict__ emb,
                             u16* __restrict__ A) {
  int m = blockIdx.x;                 // m = b*SEQ + t
  long base = (long)x[m] * EMB;
  int e4 = threadIdx.x;               // 0..127, 4 elems each
  f4 v = reinterpret_cast<const f4*>(emb + base)[e4];
  s4 o;
#pragma unroll
  for (int j = 0; j < 4; ++j) o[j] = (short)f2bf(v[j]);
  reinterpret_cast<s4*>(A + (long)m * EMB)[e4] = o;
}

static __device__ __forceinline__ void gload_lds16(const void* g, void* l) {
  __builtin_amdgcn_global_load_lds(
      (const __attribute__((address_space(1))) void*)g,
      (__attribute__((address_space(3))) void*)l, 16, 0, 0);
}

// C = A[M][K] * B[N][K]^T + bias[N]. bf16 in, f32 out. 128x128 tile, BK=32,
// global_load_lds width-16 staging. TXG=1: output row remapped to t*BATCH+b.
template<int TXG>
__global__ __launch_bounds__(256) void gemm_bt(
    const u16* __restrict__ A, const u16* __restrict__ B,
    const float* __restrict__ bias, float* __restrict__ C,
    int M, int N, int K)
{
  __shared__ u16 As[128 * 32];
  __shared__ u16 Bs[128 * 32];
  int tid  = threadIdx.x;
  int lane = tid & 63;
  int wid  = tid >> 6;
  int m0 = blockIdx.y * 128, n0 = blockIdx.x * 128;
  int wm = (wid >> 1) * 64, wn = (wid & 1) * 64;
  f32x4 acc[4][4] = {};

  int c0 = wid * 128 + lane;
  int c1 = c0 + 64;
  const u16* ga0 = A + (long)(m0 + (c0 >> 2)) * K + (c0 & 3) * 8;
  const u16* ga1 = A + (long)(m0 + (c1 >> 2)) * K + (c1 & 3) * 8;
  const u16* gb0 = B + (long)(n0 + (c0 >> 2)) * K + (c0 & 3) * 8;
  const u16* gb1 = B + (long)(n0 + (c1 >> 2)) * K + (c1 & 3) * 8;
  u16* la0 = As + wid * 1024;
  u16* la1 = la0 + 512;
  u16* lb0 = Bs + wid * 1024;
  u16* lb1 = lb0 + 512;

  for (int kt = 0; kt < K; kt += 32) {
    __syncthreads();
    gload_lds16(ga0 + kt, la0);
    gload_lds16(ga1 + kt, la1);
    gload_lds16(gb0 + kt, lb0);
    gload_lds16(gb1 + kt, lb1);
    __syncthreads();
    short8 af[4], bf[4];
#pragma unroll
    for (int i = 0; i < 4; ++i) {
      af[i] = *reinterpret_cast<const short8*>(&As[(wm + i * 16 + (lane & 15)) * 32 + ((lane >> 4) << 3)]);
      bf[i] = *reinterpret_cast<const short8*>(&Bs[(wn + i * 16 + (lane & 15)) * 32 + ((lane >> 4) << 3)]);
    }
#pragma unroll
    for (int i = 0; i < 4; ++i)
#pragma unroll
      for (int j = 0; j < 4; ++j)
        acc[i][j] = __builtin_amdgcn_mfma_f32_16x16x32_bf16(af[i], bf[j], acc[i][j], 0, 0, 0);
  }

#pragma unroll
  for (int i = 0; i < 4; ++i) {
    int m = m0 + wm + i * 16 + ((lane >> 4) << 2);
#pragma unroll
    for (int j = 0; j < 4; ++j) {
      int n = n0 + wn + j * 16 + (lane & 15);
      float bv = bias[n];
#pragma unroll
      for (int jj = 0; jj < 4; ++jj) {
        int mm = m + jj;
        long row;
        if constexpr (TXG) {
          row = (long)(mm & (SEQ - 1)) * BATCH + (mm >> 8);  // t*B + b
        } else {
          row = mm;
        }
        C[row * N + n] = acc[i][j][jj] + bv;
      }
    }
  }
}

// Persistent LSTM, 64 blocks x 256 threads, 1 block/CU, 1 wave/SIMD.
// W_hh fragments live ENTIRELY IN REGISTERS (32 short8 = 128 VGPR/lane):
// zero LDS traffic and zero bank conflicts in the loop. h exchange via
// self-certifying tagged u32 words (h_bf16 | tag<<16) through agent-scope
// relaxed atomics; consumer's polling load IS the data load. s_sleep(1)
// backoff on failed polls keeps the coherence point uncongested so publish
// stores land fast. Double-buffer WAR invariant as in r6.
__global__ __launch_bounds__(256, 1) void lstm_persist(
    const float* __restrict__ xg, const u16* __restrict__ Whh,
    const float* __restrict__ b_hh, unsigned* __restrict__ h_buf,
    u16* __restrict__ h_all)
{
  __shared__ float part[4][4][16][17];   // [wave][gate][batch][col], padded

  int tid = threadIdx.x;
  int w = tid >> 6, lane = tid & 63;
  int bid = blockIdx.x;
  int col0 = bid * 16;

  int r  = lane & 15;                 // A row (batch) / B row (gate col)
  int ko = (lane >> 4) << 3;          // k-octet within 32-wide K step

  // ---- W_hh fragments -> registers (one-time, 32 x 16B per lane) ----
  short8 Wf[8][4];
#pragma unroll
  for (int kk8 = 0; kk8 < 8; ++kk8)
#pragma unroll
    for (int g = 0; g < 4; ++g)
      Wf[kk8][g] = *reinterpret_cast<const short8*>(
          Whh + (long)(g * HID + col0 + r) * HID + (w * 256 + kk8 * 32 + ko));

  const u64* hb64 = reinterpret_cast<const u64*>(h_buf);
  // consumer: per kk needs h[r][w*256+kk*32+ko .. +7] = 4 tagged u64
  const int base_lane = w * 2048 + ((ko >> 4) << 7) + (r << 3) + ((ko & 8) >> 1);
  const int BUF64 = 8192;             // u64 words per buffer

  int eb = tid >> 4, ec = tid & 15;   // elementwise thread = (batch, col)
  const float* xgp = xg + (long)eb * GDIM + col0 + ec;
  float bias4[4];
#pragma unroll
  for (int g = 0; g < 4; ++g) bias4[g] = b_hh[g * HID + col0 + ec];
  u16* hap = h_all + (long)eb * SEQ * HID + col0 + ec;
  float creg = 0.f;

  // publish h(0)=0 with tag 1 into buf0 (this thread's own word)
  __hip_atomic_store(&h_buf[(bid << 8) + tid], 1u << 16,
                     __ATOMIC_RELAXED, __HIP_MEMORY_SCOPE_AGENT);

  float xv[4];
#pragma unroll
  for (int g = 0; g < 4; ++g) xv[g] = xgp[g * HID];   // prefetch t=0

  for (int t = 0; t < SEQ; ++t) {
    unsigned want = (unsigned)(t + 1);
    const u64* hp = hb64 + ((t & 1) ? BUF64 : 0) + base_lane;

    f32x4 a0 = {}, a1 = {}, a2 = {}, a3 = {};
#pragma unroll
    for (int ph = 0; ph < 2; ++ph) {
      u64 q[4][4];
      for (;;) {
        bool allok = true;
#pragma unroll
        for (int kk = 0; kk < 4; ++kk)
#pragma unroll
          for (int j = 0; j < 4; ++j)
            q[kk][j] = __hip_atomic_load(hp + (ph * 4 + kk) * 256 + j,
                                         __ATOMIC_RELAXED, __HIP_MEMORY_SCOPE_AGENT);
#pragma unroll
        for (int kk = 0; kk < 4; ++kk)
#pragma unroll
          for (int j = 0; j < 4; ++j) {
            allok = allok && (((unsigned)(q[kk][j] >> 16) & 0xffffu) >= want);
            allok = allok && ((unsigned)(q[kk][j] >> 48) >= want);
          }
        if (__all(allok)) break;
        __builtin_amdgcn_s_sleep(1);     // throttle: keep coherence point clear
      }

#pragma unroll
      for (int kk = 0; kk < 4; ++kk) {
        u32x4 wv;
#pragma unroll
        for (int j = 0; j < 4; ++j)
          wv[j] = ((unsigned)(q[kk][j] & 0xffffu)) |
                  ((unsigned)(q[kk][j] >> 16) & 0xffff0000u);
        short8 av = __builtin_bit_cast(short8, wv);
        a0 = __builtin_amdgcn_mfma_f32_16x16x32_bf16(av, Wf[ph * 4 + kk][0], a0, 0, 0, 0);
        a1 = __builtin_amdgcn_mfma_f32_16x16x32_bf16(av, Wf[ph * 4 + kk][1], a1, 0, 0, 0);
        a2 = __builtin_amdgcn_mfma_f32_16x16x32_bf16(av, Wf[ph * 4 + kk][2], a2, 0, 0, 0);
        a3 = __builtin_amdgcn_mfma_f32_16x16x32_bf16(av, Wf[ph * 4 + kk][3], a3, 0, 0, 0);
      }
    }

#pragma unroll
    for (int j = 0; j < 4; ++j) {
      int batch = ((lane >> 4) << 2) + j;
      part[w][0][batch][lane & 15] = a0[j];
      part[w][1][batch][lane & 15] = a1[j];
      part[w][2][batch][lane & 15] = a2[j];
      part[w][3][batch][lane & 15] = a3[j];
    }
    __syncthreads();                       // (A) partials visible; also
                                           // certifies all h(t) tags were seen
    // ---- elementwise ----
    float pre[4];
#pragma unroll
    for (int g = 0; g < 4; ++g)
      pre[g] = part[0][g][eb][ec] + part[1][g][eb][ec] +
               part[2][g][eb][ec] + part[3][g][eb][ec] + xv[g] + bias4[g];
    float i_ = fsig(pre[0]);
    float f_ = fsig(pre[1]);
    float g_ = ftanh(pre[2]);
    float o_ = fsig(pre[3]);
    float cn = f_ * creg + i_ * g_;
    creg = cn;
    u16 hbf = f2bf(o_ * ftanh(cn));

    // ---- publish h(t+1): one self-tagged u32, fire-and-forget ----
    if (t + 1 < SEQ) {
      unsigned word = (unsigned)hbf | ((unsigned)(t + 2) << 16);
      __hip_atomic_store(&h_buf[(((t + 1) & 1) << 14) + (bid << 8) + tid], word,
                         __ATOMIC_RELAXED, __HIP_MEMORY_SCOPE_AGENT);
    }

    // ---- off-critical-path: h_all store + next xg prefetch ----
    hap[(long)t * HID] = hbf;
    int tn = (t + 1 < SEQ) ? t + 1 : t;
#pragma unroll
    for (int g = 0; g < 4; ++g)
      xv[g] = xgp[(long)tn * BATCH * GDIM + g * HID];

    __syncthreads();                       // keep waves step-aligned
  }
}

extern "C" void kernel_launch(void* const* d_in, const int* in_sizes, int n_in,
                              void* d_out, int out_size, void* d_ws, size_t ws_size,
                              hipStream_t stream) {
  const int*   x      = (const int*)d_in[0];
  const float* emb    = (const float*)d_in[1];
  const float* W_ih   = (const float*)d_in[2];
  const float* W_hh   = (const float*)d_in[3];
  const float* b_ih   = (const float*)d_in[4];
  const float* b_hh   = (const float*)d_in[5];
  const float* head_W = (const float*)d_in[6];
  const float* head_b = (const float*)d_in[7];
  float* out = (float*)d_out;

  char* ws = (char*)d_ws;
  size_t off = 0;
  auto alloc = [&](size_t bytes) -> void* {
    void* p = ws + off;
    off += (bytes + 255) & ~(size_t)255;
    return p;
  };
  u16*      Aemb  = (u16*)alloc((size_t)MTOT * EMB * 2);
  u16*      Wih_b = (u16*)alloc((size_t)GDIM * EMB * 2);
  u16*      Whh_b = (u16*)alloc((size_t)GDIM * HID * 2);
  u16*      HW_b  = (u16*)alloc((size_t)VOCAB * HID * 2);
  float*    xg    = (float*)alloc((size_t)MTOT * GDIM * 4);   // time-major [T][B][4H]
  u16*      h_all = (u16*)alloc((size_t)MTOT * HID * 2);
  unsigned* h_buf = (unsigned*)alloc((size_t)2 * NBLK * 256 * 4); // [2][64][16][16] tagged u32

  // zero tags (harness poisons ws with 0xAA -> would fake tags otherwise)
  hipMemsetAsync(h_buf, 0, (size_t)2 * NBLK * 256 * 4, stream);

  cvt_bf16_v4<<<1024, 256, 0, stream>>>(W_ih, Wih_b, (long)GDIM * EMB / 4);
  cvt_bf16_v4<<<1024, 256, 0, stream>>>(W_hh, Whh_b, (long)GDIM * HID / 4);
  cvt_bf16_v4<<<2048, 256, 0, stream>>>(head_W, HW_b, (long)VOCAB * HID / 4);
  embed_gather<<<MTOT, 128, 0, stream>>>(x, emb, Aemb);

  gemm_bt<1><<<dim3(GDIM / 128, MTOT / 128), 256, 0, stream>>>(
      Aemb, Wih_b, b_ih, xg, MTOT, GDIM, EMB);

  {
    const float* xgc = xg;
    const u16* whc = Whh_b;
    void* args[] = {(void*)&xgc, (void*)&whc, (void*)&b_hh,
                    (void*)&h_buf, (void*)&h_all};
    hipLaunchCooperativeKernel((const void*)lstm_persist, dim3(NBLK), dim3(256),
                               args, 0, stream);
  }

  gemm_bt<0><<<dim3(VOCAB / 128, MTOT / 128), 256, 0, stream>>>(
      h_all, HW_b, head_b, out, MTOT, VOCAB, HID);
}

// Round 8
// 1241.431 us; speedup vs baseline: 4.3656x; 1.2122x over previous
//
#include <hip/hip_runtime.h>
#include <hip/hip_bf16.h>
#include <cstdint>
#include <cstddef>

typedef __attribute__((ext_vector_type(8))) short short8;
typedef __attribute__((ext_vector_type(4))) float f32x4;
typedef __attribute__((ext_vector_type(4))) float f4;
typedef __attribute__((ext_vector_type(4))) short s4;
typedef __attribute__((ext_vector_type(4))) unsigned u32x4;
typedef unsigned short u16;
typedef unsigned long long u64;

#define VOCAB 32000
#define EMB   512
#define HID   1024
#define GDIM  4096   // 4*HID
#define BATCH 16
#define SEQ   256
#define MTOT  4096   // BATCH*SEQ
#define NBLK  64     // lstm blocks

#define SLAB  4096          // bytes per producer slab (1KB data + 3KB pad)
#define BUFB  (NBLK * SLAB) // bytes per h buffer (256 KB)

static __device__ __forceinline__ u16 f2bf(float f) {
  unsigned u = __builtin_bit_cast(unsigned, f);
  u += 0x7fffu + ((u >> 16) & 1u);   // RNE
  return (u16)(u >> 16);
}

static __device__ __forceinline__ float fsig(float x) {
  return __builtin_amdgcn_rcpf(1.f + __expf(-x));
}
static __device__ __forceinline__ float ftanh(float x) {
  return 1.f - 2.f * __builtin_amdgcn_rcpf(1.f + __expf(2.f * x));
}

__global__ void cvt_bf16_v4(const float* __restrict__ in, u16* __restrict__ out, long n4) {
  long i = (long)blockIdx.x * blockDim.x + threadIdx.x;
  long stride = (long)gridDim.x * blockDim.x;
  for (; i < n4; i += stride) {
    f4 v = reinterpret_cast<const f4*>(in)[i];
    s4 o;
#pragma unroll
    for (int j = 0; j < 4; ++j) o[j] = (short)f2bf(v[j]);
    reinterpret_cast<s4*>(out)[i] = o;
  }
}

__global__ void embed_gather(const int* __restrict__ x, const float* __restrict__ emb,
                             u16* __restrict__ A) {
  int m = blockIdx.x;                 // m = b*SEQ + t
  long base = (long)x[m] * EMB;
  int e4 = threadIdx.x;               // 0..127, 4 elems each
  f4 v = reinterpret_cast<const f4*>(emb + base)[e4];
  s4 o;
#pragma unroll
  for (int j = 0; j < 4; ++j) o[j] = (short)f2bf(v[j]);
  reinterpret_cast<s4*>(A + (long)m * EMB)[e4] = o;
}

static __device__ __forceinline__ void gload_lds16(const void* g, void* l) {
  __builtin_amdgcn_global_load_lds(
      (const __attribute__((address_space(1))) void*)g,
      (__attribute__((address_space(3))) void*)l, 16, 0, 0);
}

// C = A[M][K] * B[N][K]^T + bias[N]. bf16 in, f32 out. 128x128 tile, BK=32,
// global_load_lds width-16 staging. TXG=1: output row remapped to t*BATCH+b.
template<int TXG>
__global__ __launch_bounds__(256) void gemm_bt(
    const u16* __restrict__ A, const u16* __restrict__ B,
    const float* __restrict__ bias, float* __restrict__ C,
    int M, int N, int K)
{
  __shared__ u16 As[128 * 32];
  __shared__ u16 Bs[128 * 32];
  int tid  = threadIdx.x;
  int lane = tid & 63;
  int wid  = tid >> 6;
  int m0 = blockIdx.y * 128, n0 = blockIdx.x * 128;
  int wm = (wid >> 1) * 64, wn = (wid & 1) * 64;
  f32x4 acc[4][4] = {};

  int c0 = wid * 128 + lane;
  int c1 = c0 + 64;
  const u16* ga0 = A + (long)(m0 + (c0 >> 2)) * K + (c0 & 3) * 8;
  const u16* ga1 = A + (long)(m0 + (c1 >> 2)) * K + (c1 & 3) * 8;
  const u16* gb0 = B + (long)(n0 + (c0 >> 2)) * K + (c0 & 3) * 8;
  const u16* gb1 = B + (long)(n0 + (c1 >> 2)) * K + (c1 & 3) * 8;
  u16* la0 = As + wid * 1024;
  u16* la1 = la0 + 512;
  u16* lb0 = Bs + wid * 1024;
  u16* lb1 = lb0 + 512;

  for (int kt = 0; kt < K; kt += 32) {
    __syncthreads();
    gload_lds16(ga0 + kt, la0);
    gload_lds16(ga1 + kt, la1);
    gload_lds16(gb0 + kt, lb0);
    gload_lds16(gb1 + kt, lb1);
    __syncthreads();
    short8 af[4], bf[4];
#pragma unroll
    for (int i = 0; i < 4; ++i) {
      af[i] = *reinterpret_cast<const short8*>(&As[(wm + i * 16 + (lane & 15)) * 32 + ((lane >> 4) << 3)]);
      bf[i] = *reinterpret_cast<const short8*>(&Bs[(wn + i * 16 + (lane & 15)) * 32 + ((lane >> 4) << 3)]);
    }
#pragma unroll
    for (int i = 0; i < 4; ++i)
#pragma unroll
      for (int j = 0; j < 4; ++j)
        acc[i][j] = __builtin_amdgcn_mfma_f32_16x16x32_bf16(af[i], bf[j], acc[i][j], 0, 0, 0);
  }

#pragma unroll
  for (int i = 0; i < 4; ++i) {
    int m = m0 + wm + i * 16 + ((lane >> 4) << 2);
#pragma unroll
    for (int j = 0; j < 4; ++j) {
      int n = n0 + wn + j * 16 + (lane & 15);
      float bv = bias[n];
#pragma unroll
      for (int jj = 0; jj < 4; ++jj) {
        int mm = m + jj;
        long row;
        if constexpr (TXG) {
          row = (long)(mm & (SEQ - 1)) * BATCH + (mm >> 8);  // t*B + b
        } else {
          row = mm;
        }
        C[row * N + n] = acc[i][j][jj] + bv;
      }
    }
  }
}

// Persistent LSTM, 64 blocks x 256 threads, 1 block/CU, 1 wave/SIMD.
// W_hh fragments in registers. h exchange via self-certifying tagged u32s
// (h_bf16 | tag<<16) in PADDED per-producer slabs (4 KB stride, spreads LLC
// slices). Consumer reads are 16-byte device-scope (sc1) vector loads —
// half the request count of 8B atomics; tags re-certify every word, torn
// reads impossible at u32 granularity, stale reads retried.
__global__ __launch_bounds__(256, 1) void lstm_persist(
    const float* __restrict__ xg, const u16* __restrict__ Whh,
    const float* __restrict__ b_hh, unsigned* __restrict__ h_buf,
    u16* __restrict__ h_all)
{
  __shared__ float part[4][4][16][17];   // [wave][gate][batch][col], padded

  int tid = threadIdx.x;
  int w = tid >> 6, lane = tid & 63;
  int bid = blockIdx.x;
  int col0 = bid * 16;

  int r  = lane & 15;                 // A row (batch) / B row (gate col)
  int ko = (lane >> 4) << 3;          // k-octet within 32-wide K step

  // ---- W_hh fragments -> registers (one-time, 32 x 16B per lane) ----
  short8 Wf[8][4];
#pragma unroll
  for (int kk8 = 0; kk8 < 8; ++kk8)
#pragma unroll
    for (int g = 0; g < 4; ++g)
      Wf[kk8][g] = *reinterpret_cast<const short8*>(
          Whh + (long)(g * HID + col0 + r) * HID + (w * 256 + kk8 * 32 + ko));

  // per-lane slab byte offsets for the 8 (ph,kk) chunks:
  // producer p = w*16 + ph*8 + kk*2 + (ko>>4); chunk at p*SLAB + r*64 + (ko&8)*4
  unsigned soff[2][4];
#pragma unroll
  for (int ph = 0; ph < 2; ++ph)
#pragma unroll
    for (int kk = 0; kk < 4; ++kk) {
      int p = w * 16 + ph * 8 + kk * 2 + (ko >> 4);
      soff[ph][kk] = (unsigned)(p * SLAB + r * 64 + (ko & 8) * 4);
    }
  const char* hbase = reinterpret_cast<const char*>(h_buf);

  int eb = tid >> 4, ec = tid & 15;   // elementwise thread = (batch, col)
  const float* xgp = xg + (long)eb * GDIM + col0 + ec;
  float bias4[4];
#pragma unroll
  for (int g = 0; g < 4; ++g) bias4[g] = b_hh[g * HID + col0 + ec];
  u16* hap = h_all + (long)eb * SEQ * HID + col0 + ec;
  float creg = 0.f;

  // publish h(0)=0 with tag 1 into buf0 (this thread's own word)
  __hip_atomic_store(&h_buf[(bid * SLAB / 4) + tid], 1u << 16,
                     __ATOMIC_RELAXED, __HIP_MEMORY_SCOPE_AGENT);

  float xv[4];
#pragma unroll
  for (int g = 0; g < 4; ++g) xv[g] = xgp[g * HID];   // prefetch t=0

  for (int t = 0; t < SEQ; ++t) {
    unsigned want = (unsigned)(t + 1);
    const char* hb = hbase + ((t & 1) ? BUFB : 0);

    f32x4 a0 = {}, a1 = {}, a2 = {}, a3 = {};
#pragma unroll
    for (int ph = 0; ph < 2; ++ph) {
      u32x4 q[4][2];
      for (;;) {
#pragma unroll
        for (int kk = 0; kk < 4; ++kk) {
          const void* a = hb + soff[ph][kk];
          const void* b = hb + soff[ph][kk] + 16;
          asm volatile("global_load_dwordx4 %0, %1, off sc1"
                       : "=v"(q[kk][0]) : "v"(a));
          asm volatile("global_load_dwordx4 %0, %1, off sc1"
                       : "=v"(q[kk][1]) : "v"(b));
        }
        asm volatile("s_waitcnt vmcnt(0)" ::: "memory");
        __builtin_amdgcn_sched_barrier(0);
        bool allok = true;
#pragma unroll
        for (int kk = 0; kk < 4; ++kk)
#pragma unroll
          for (int v = 0; v < 2; ++v)
#pragma unroll
            for (int j = 0; j < 4; ++j)
              allok = allok && ((q[kk][v][j] >> 16) >= want);
        if (__all(allok)) break;
        __builtin_amdgcn_s_sleep(1);     // throttle the coherence point
      }

#pragma unroll
      for (int kk = 0; kk < 4; ++kk) {
        u32x4 wv;
        wv[0] = (q[kk][0][0] & 0xffffu) | (q[kk][0][1] << 16);
        wv[1] = (q[kk][0][2] & 0xffffu) | (q[kk][0][3] << 16);
        wv[2] = (q[kk][1][0] & 0xffffu) | (q[kk][1][1] << 16);
        wv[3] = (q[kk][1][2] & 0xffffu) | (q[kk][1][3] << 16);
        short8 av = __builtin_bit_cast(short8, wv);
        a0 = __builtin_amdgcn_mfma_f32_16x16x32_bf16(av, Wf[ph * 4 + kk][0], a0, 0, 0, 0);
        a1 = __builtin_amdgcn_mfma_f32_16x16x32_bf16(av, Wf[ph * 4 + kk][1], a1, 0, 0, 0);
        a2 = __builtin_amdgcn_mfma_f32_16x16x32_bf16(av, Wf[ph * 4 + kk][2], a2, 0, 0, 0);
        a3 = __builtin_amdgcn_mfma_f32_16x16x32_bf16(av, Wf[ph * 4 + kk][3], a3, 0, 0, 0);
      }
    }

#pragma unroll
    for (int j = 0; j < 4; ++j) {
      int batch = ((lane >> 4) << 2) + j;
      part[w][0][batch][lane & 15] = a0[j];
      part[w][1][batch][lane & 15] = a1[j];
      part[w][2][batch][lane & 15] = a2[j];
      part[w][3][batch][lane & 15] = a3[j];
    }
    __syncthreads();                       // (A) partials visible; also
                                           // certifies all h(t) tags were seen
    // ---- elementwise ----
    float pre[4];
#pragma unroll
    for (int g = 0; g < 4; ++g)
      pre[g] = part[0][g][eb][ec] + part[1][g][eb][ec] +
               part[2][g][eb][ec] + part[3][g][eb][ec] + xv[g] + bias4[g];
    float i_ = fsig(pre[0]);
    float f_ = fsig(pre[1]);
    float g_ = ftanh(pre[2]);
    float o_ = fsig(pre[3]);
    float cn = f_ * creg + i_ * g_;
    creg = cn;
    u16 hbf = f2bf(o_ * ftanh(cn));

    // ---- publish h(t+1): one self-tagged u32, fire-and-forget ----
    if (t + 1 < SEQ) {
      unsigned word = (unsigned)hbf | ((unsigned)(t + 2) << 16);
      __hip_atomic_store(
          &h_buf[(((t + 1) & 1) ? BUFB / 4 : 0) + (bid * SLAB / 4) + tid],
          word, __ATOMIC_RELAXED, __HIP_MEMORY_SCOPE_AGENT);
    }

    // ---- off-critical-path: h_all store + next xg prefetch ----
    hap[(long)t * HID] = hbf;
    int tn = (t + 1 < SEQ) ? t + 1 : t;
#pragma unroll
    for (int g = 0; g < 4; ++g)
      xv[g] = xgp[(long)tn * BATCH * GDIM + g * HID];

    __syncthreads();                       // keep waves step-aligned
  }
}

extern "C" void kernel_launch(void* const* d_in, const int* in_sizes, int n_in,
                              void* d_out, int out_size, void* d_ws, size_t ws_size,
                              hipStream_t stream) {
  const int*   x      = (const int*)d_in[0];
  const float* emb    = (const float*)d_in[1];
  const float* W_ih   = (const float*)d_in[2];
  const float* W_hh   = (const float*)d_in[3];
  const float* b_ih   = (const float*)d_in[4];
  const float* b_hh   = (const float*)d_in[5];
  const float* head_W = (const float*)d_in[6];
  const float* head_b = (const float*)d_in[7];
  float* out = (float*)d_out;

  char* ws = (char*)d_ws;
  size_t off = 0;
  auto alloc = [&](size_t bytes) -> void* {
    void* p = ws + off;
    off += (bytes + 255) & ~(size_t)255;
    return p;
  };
  u16*      Aemb  = (u16*)alloc((size_t)MTOT * EMB * 2);
  u16*      Wih_b = (u16*)alloc((size_t)GDIM * EMB * 2);
  u16*      Whh_b = (u16*)alloc((size_t)GDIM * HID * 2);
  u16*      HW_b  = (u16*)alloc((size_t)VOCAB * HID * 2);
  float*    xg    = (float*)alloc((size_t)MTOT * GDIM * 4);   // time-major [T][B][4H]
  u16*      h_all = (u16*)alloc((size_t)MTOT * HID * 2);
  unsigned* h_buf = (unsigned*)alloc((size_t)2 * BUFB);       // padded tagged slabs

  // zero tags (harness poisons ws with 0xAA -> would fake tags otherwise)
  hipMemsetAsync(h_buf, 0, (size_t)2 * BUFB, stream);

  cvt_bf16_v4<<<1024, 256, 0, stream>>>(W_ih, Wih_b, (long)GDIM * EMB / 4);
  cvt_bf16_v4<<<1024, 256, 0, stream>>>(W_hh, Whh_b, (long)GDIM * HID / 4);
  cvt_bf16_v4<<<2048, 256, 0, stream>>>(head_W, HW_b, (long)VOCAB * HID / 4);
  embed_gather<<<MTOT, 128, 0, stream>>>(x, emb, Aemb);

  gemm_bt<1><<<dim3(GDIM / 128, MTOT / 128), 256, 0, stream>>>(
      Aemb, Wih_b, b_ih, xg, MTOT, GDIM, EMB);

  {
    const float* xgc = xg;
    const u16* whc = Whh_b;
    void* args[] = {(void*)&xgc, (void*)&whc, (void*)&b_hh,
                    (void*)&h_buf, (void*)&h_all};
    hipLaunchCooperativeKernel((const void*)lstm_persist, dim3(NBLK), dim3(256),
                               args, 0, stream);
  }

  gemm_bt<0><<<dim3(VOCAB / 128, MTOT / 128), 256, 0, stream>>>(
      h_all, HW_b, head_b, out, MTOT, VOCAB, HID);
}

// Round 10
// 1199.330 us; speedup vs baseline: 4.5188x; 1.0351x over previous
//
#include <hip/hip_runtime.h>
#include <hip/hip_bf16.h>
#include <cstdint>
#include <cstddef>

typedef __attribute__((ext_vector_type(8))) short short8;
typedef __attribute__((ext_vector_type(4))) float f32x4;
typedef __attribute__((ext_vector_type(4))) float f4;
typedef __attribute__((ext_vector_type(4))) short s4;
typedef __attribute__((ext_vector_type(4))) unsigned u32x4;
typedef unsigned short u16;
typedef unsigned long long u64;

#define VOCAB 32000
#define EMB   512
#define HID   1024
#define GDIM  4096   // 4*HID
#define BATCH 16
#define SEQ   256
#define MTOT  4096   // BATCH*SEQ
#define NBLK  64     // lstm blocks

#define SLAB  4096          // bytes per producer slab (1KB data + 3KB pad)
#define BUFB  (NBLK * SLAB) // bytes per h buffer (256 KB)

static __device__ __forceinline__ u16 f2bf(float f) {
  unsigned u = __builtin_bit_cast(unsigned, f);
  u += 0x7fffu + ((u >> 16) & 1u);   // RNE
  return (u16)(u >> 16);
}

static __device__ __forceinline__ float fsig(float x) {
  return __builtin_amdgcn_rcpf(1.f + __expf(-x));
}
static __device__ __forceinline__ float ftanh(float x) {
  return 1.f - 2.f * __builtin_amdgcn_rcpf(1.f + __expf(2.f * x));
}

__global__ void cvt_bf16_v4(const float* __restrict__ in, u16* __restrict__ out, long n4) {
  long i = (long)blockIdx.x * blockDim.x + threadIdx.x;
  long stride = (long)gridDim.x * blockDim.x;
  for (; i < n4; i += stride) {
    f4 v = reinterpret_cast<const f4*>(in)[i];
    s4 o;
#pragma unroll
    for (int j = 0; j < 4; ++j) o[j] = (short)f2bf(v[j]);
    reinterpret_cast<s4*>(out)[i] = o;
  }
}

__global__ void embed_gather(const int* __restrict__ x, const float* __restrict__ emb,
                             u16* __restrict__ A) {
  int m = blockIdx.x;                 // m = b*SEQ + t
  long base = (long)x[m] * EMB;
  int e4 = threadIdx.x;               // 0..127, 4 elems each
  f4 v = reinterpret_cast<const f4*>(emb + base)[e4];
  s4 o;
#pragma unroll
  for (int j = 0; j < 4; ++j) o[j] = (short)f2bf(v[j]);
  reinterpret_cast<s4*>(A + (long)m * EMB)[e4] = o;
}

static __device__ __forceinline__ void gload_lds16(const void* g, void* l) {
  __builtin_amdgcn_global_load_lds(
      (const __attribute__((address_space(1))) void*)g,
      (__attribute__((address_space(3))) void*)l, 16, 0, 0);
}

// C = A[M][K] * B[N][K]^T + bias[N]. bf16 in, f32 out. 128x128 tile, BK=64,
// global_load_lds width-16 staging with T2 XOR swizzle applied via
// PRE-SWIZZLED GLOBAL SOURCE (linear LDS dest, rule #21) + swizzled ds_read.
// Swizzle: 16B-chunk index g (0..7 within a 128B row) stored at pg = g^(row&7).
// Bijective XCD swizzle on the grid (requires nwg % 8 == 0).
// TXG=1: output row remapped to t*BATCH+b (time-major xg).
template<int TXG>
__global__ __launch_bounds__(256) void gemm_bt(
    const u16* __restrict__ A, const u16* __restrict__ B,
    const float* __restrict__ bias, float* __restrict__ C,
    int M, int N, int K)
{
  __shared__ u16 As[128 * 64];
  __shared__ u16 Bs[128 * 64];
  int tid  = threadIdx.x;
  int lane = tid & 63;
  int wid  = tid >> 6;

  // XCD-aware bijective grid swizzle (nwg % 8 == 0 for both call sites)
  int nwg = gridDim.x * gridDim.y;
  int id  = blockIdx.y * gridDim.x + blockIdx.x;
  int id2 = (id & 7) * (nwg >> 3) + (id >> 3);
  int bx  = id2 % gridDim.x, by = id2 / gridDim.x;
  int m0 = by * 128, n0 = bx * 128;

  int wm = (wid >> 1) * 64, wn = (wid & 1) * 64;
  int r  = lane & 15;
  int hi = lane >> 4;
  f32x4 acc[4][4] = {};

  // staging: 16B chunk c in [0,1024): row = c>>3, phys grp = c&7,
  // logical grp = (c&7) ^ (row&7)  (inverse swizzle on the source address)
  const u16* gaj[4];
  const u16* gbj[4];
  u16* laj[4];
  u16* lbj[4];
#pragma unroll
  for (int j = 0; j < 4; ++j) {
    int c   = wid * 256 + j * 64 + lane;
    int row = c >> 3;
    int gl  = (c & 7) ^ (row & 7);
    gaj[j] = A + (long)(m0 + row) * K + gl * 8;
    gbj[j] = B + (long)(n0 + row) * K + gl * 8;
    laj[j] = As + wid * 2048 + j * 512;   // wave-uniform linear dest
    lbj[j] = Bs + wid * 2048 + j * 512;
  }

  for (int kt = 0; kt < K; kt += 64) {
    __syncthreads();
#pragma unroll
    for (int j = 0; j < 4; ++j) {
      gload_lds16(gaj[j] + kt, laj[j]);
      gload_lds16(gbj[j] + kt, lbj[j]);
    }
    __syncthreads();
    short8 af[2][4], bf[2][4];
#pragma unroll
    for (int ks = 0; ks < 2; ++ks)
#pragma unroll
      for (int i = 0; i < 4; ++i) {
        int ra = wm + i * 16 + r;
        int rb = wn + i * 16 + r;
        af[ks][i] = *reinterpret_cast<const short8*>(
            &As[ra * 64 + ((ks * 4 + hi) ^ (ra & 7)) * 8]);
        bf[ks][i] = *reinterpret_cast<const short8*>(
            &Bs[rb * 64 + ((ks * 4 + hi) ^ (rb & 7)) * 8]);
      }
#pragma unroll
    for (int ks = 0; ks < 2; ++ks)
#pragma unroll
      for (int i = 0; i < 4; ++i)
#pragma unroll
        for (int j = 0; j < 4; ++j)
          acc[i][j] = __builtin_amdgcn_mfma_f32_16x16x32_bf16(
              af[ks][i], bf[ks][j], acc[i][j], 0, 0, 0);
  }

#pragma unroll
  for (int i = 0; i < 4; ++i) {
    int m = m0 + wm + i * 16 + (hi << 2);
#pragma unroll
    for (int j = 0; j < 4; ++j) {
      int n = n0 + wn + j * 16 + r;
      float bv = bias[n];
#pragma unroll
      for (int jj = 0; jj < 4; ++jj) {
        int mm = m + jj;
        long row;
        if constexpr (TXG) {
          row = (long)(mm & (SEQ - 1)) * BATCH + (mm >> 8);  // t*B + b
        } else {
          row = mm;
        }
        C[row * N + n] = acc[i][j][jj] + bv;
      }
    }
  }
}

// Persistent LSTM (r8 verbatim — known good, 720 us). 64 blocks x 256
// threads, 1 block/CU. W_hh fragments in registers. h exchange via
// self-certifying tagged u32s (h_bf16 | tag<<16) in padded 4KB slabs;
// consumer reads are 16B sc1 vector loads; tags fail CLOSED (stale -> retry).
__global__ __launch_bounds__(256, 1) void lstm_persist(
    const float* __restrict__ xg, const u16* __restrict__ Whh,
    const float* __restrict__ b_hh, unsigned* __restrict__ h_buf,
    u16* __restrict__ h_all)
{
  __shared__ float part[4][4][16][17];   // [wave][gate][batch][col], padded

  int tid = threadIdx.x;
  int w = tid >> 6, lane = tid & 63;
  int bid = blockIdx.x;
  int col0 = bid * 16;

  int r  = lane & 15;                 // A row (batch) / B row (gate col)
  int ko = (lane >> 4) << 3;          // k-octet within 32-wide K step

  // ---- W_hh fragments -> registers (one-time, 32 x 16B per lane) ----
  short8 Wf[8][4];
#pragma unroll
  for (int kk8 = 0; kk8 < 8; ++kk8)
#pragma unroll
    for (int g = 0; g < 4; ++g)
      Wf[kk8][g] = *reinterpret_cast<const short8*>(
          Whh + (long)(g * HID + col0 + r) * HID + (w * 256 + kk8 * 32 + ko));

  // per-lane slab byte offsets for the 8 (ph,kk) chunks:
  // producer p = w*16 + ph*8 + kk*2 + (ko>>4); chunk at p*SLAB + r*64 + (ko&8)*4
  unsigned soff[2][4];
#pragma unroll
  for (int ph = 0; ph < 2; ++ph)
#pragma unroll
    for (int kk = 0; kk < 4; ++kk) {
      int p = w * 16 + ph * 8 + kk * 2 + (ko >> 4);
      soff[ph][kk] = (unsigned)(p * SLAB + r * 64 + (ko & 8) * 4);
    }
  const char* hbase = reinterpret_cast<const char*>(h_buf);

  int eb = tid >> 4, ec = tid & 15;   // elementwise thread = (batch, col)
  const float* xgp = xg + (long)eb * GDIM + col0 + ec;
  float bias4[4];
#pragma unroll
  for (int g = 0; g < 4; ++g) bias4[g] = b_hh[g * HID + col0 + ec];
  u16* hap = h_all + (long)eb * SEQ * HID + col0 + ec;
  float creg = 0.f;

  // publish h(0)=0 with tag 1 into buf0 (this thread's own word)
  __hip_atomic_store(&h_buf[(bid * SLAB / 4) + tid], 1u << 16,
                     __ATOMIC_RELAXED, __HIP_MEMORY_SCOPE_AGENT);

  float xv[4];
#pragma unroll
  for (int g = 0; g < 4; ++g) xv[g] = xgp[g * HID];   // prefetch t=0

  for (int t = 0; t < SEQ; ++t) {
    unsigned want = (unsigned)(t + 1);
    const char* hb = hbase + ((t & 1) ? BUFB : 0);

    f32x4 a0 = {}, a1 = {}, a2 = {}, a3 = {};
#pragma unroll
    for (int ph = 0; ph < 2; ++ph) {
      u32x4 q[4][2];
      for (;;) {
#pragma unroll
        for (int kk = 0; kk < 4; ++kk) {
          const void* a = hb + soff[ph][kk];
          const void* b = hb + soff[ph][kk] + 16;
          asm volatile("global_load_dwordx4 %0, %1, off sc1"
                       : "=v"(q[kk][0]) : "v"(a));
          asm volatile("global_load_dwordx4 %0, %1, off sc1"
                       : "=v"(q[kk][1]) : "v"(b));
        }
        asm volatile("s_waitcnt vmcnt(0)" ::: "memory");
        __builtin_amdgcn_sched_barrier(0);
        bool allok = true;
#pragma unroll
        for (int kk = 0; kk < 4; ++kk)
#pragma unroll
          for (int v = 0; v < 2; ++v)
#pragma unroll
            for (int j = 0; j < 4; ++j)
              allok = allok && ((q[kk][v][j] >> 16) >= want);
        if (__all(allok)) break;
        __builtin_amdgcn_s_sleep(1);     // throttle the coherence point
      }

#pragma unroll
      for (int kk = 0; kk < 4; ++kk) {
        u32x4 wv;
        wv[0] = (q[kk][0][0] & 0xffffu) | (q[kk][0][1] << 16);
        wv[1] = (q[kk][0][2] & 0xffffu) | (q[kk][0][3] << 16);
        wv[2] = (q[kk][1][0] & 0xffffu) | (q[kk][1][1] << 16);
        wv[3] = (q[kk][1][2] & 0xffffu) | (q[kk][1][3] << 16);
        short8 av = __builtin_bit_cast(short8, wv);
        a0 = __builtin_amdgcn_mfma_f32_16x16x32_bf16(av, Wf[ph * 4 + kk][0], a0, 0, 0, 0);
        a1 = __builtin_amdgcn_mfma_f32_16x16x32_bf16(av, Wf[ph * 4 + kk][1], a1, 0, 0, 0);
        a2 = __builtin_amdgcn_mfma_f32_16x16x32_bf16(av, Wf[ph * 4 + kk][2], a2, 0, 0, 0);
        a3 = __builtin_amdgcn_mfma_f32_16x16x32_bf16(av, Wf[ph * 4 + kk][3], a3, 0, 0, 0);
      }
    }

#pragma unroll
    for (int j = 0; j < 4; ++j) {
      int batch = ((lane >> 4) << 2) + j;
      part[w][0][batch][lane & 15] = a0[j];
      part[w][1][batch][lane & 15] = a1[j];
      part[w][2][batch][lane & 15] = a2[j];
      part[w][3][batch][lane & 15] = a3[j];
    }
    __syncthreads();                       // (A) partials visible; also
                                           // certifies all h(t) tags were seen
    // ---- elementwise ----
    float pre[4];
#pragma unroll
    for (int g = 0; g < 4; ++g)
      pre[g] = part[0][g][eb][ec] + part[1][g][eb][ec] +
               part[2][g][eb][ec] + part[3][g][eb][ec] + xv[g] + bias4[g];
    float i_ = fsig(pre[0]);
    float f_ = fsig(pre[1]);
    float g_ = ftanh(pre[2]);
    float o_ = fsig(pre[3]);
    float cn = f_ * creg + i_ * g_;
    creg = cn;
    u16 hbf = f2bf(o_ * ftanh(cn));

    // ---- publish h(t+1): one self-tagged u32, fire-and-forget ----
    if (t + 1 < SEQ) {
      unsigned word = (unsigned)hbf | ((unsigned)(t + 2) << 16);
      __hip_atomic_store(
          &h_buf[(((t + 1) & 1) ? BUFB / 4 : 0) + (bid * SLAB / 4) + tid],
          word, __ATOMIC_RELAXED, __HIP_MEMORY_SCOPE_AGENT);
    }

    // ---- off-critical-path: h_all store + next xg prefetch ----
    hap[(long)t * HID] = hbf;
    int tn = (t + 1 < SEQ) ? t + 1 : t;
#pragma unroll
    for (int g = 0; g < 4; ++g)
      xv[g] = xgp[(long)tn * BATCH * GDIM + g * HID];

    __syncthreads();                       // keep waves step-aligned
  }
}

extern "C" void kernel_launch(void* const* d_in, const int* in_sizes, int n_in,
                              void* d_out, int out_size, void* d_ws, size_t ws_size,
                              hipStream_t stream) {
  const int*   x      = (const int*)d_in[0];
  const float* emb    = (const float*)d_in[1];
  const float* W_ih   = (const float*)d_in[2];
  const float* W_hh   = (const float*)d_in[3];
  const float* b_ih   = (const float*)d_in[4];
  const float* b_hh   = (const float*)d_in[5];
  const float* head_W = (const float*)d_in[6];
  const float* head_b = (const float*)d_in[7];
  float* out = (float*)d_out;

  char* ws = (char*)d_ws;
  size_t off = 0;
  auto alloc = [&](size_t bytes) -> void* {
    void* p = ws + off;
    off += (bytes + 255) & ~(size_t)255;
    return p;
  };
  u16*      Aemb  = (u16*)alloc((size_t)MTOT * EMB * 2);
  u16*      Wih_b = (u16*)alloc((size_t)GDIM * EMB * 2);
  u16*      Whh_b = (u16*)alloc((size_t)GDIM * HID * 2);
  u16*      HW_b  = (u16*)alloc((size_t)VOCAB * HID * 2);
  float*    xg    = (float*)alloc((size_t)MTOT * GDIM * 4);   // time-major [T][B][4H]
  u16*      h_all = (u16*)alloc((size_t)MTOT * HID * 2);
  unsigned* h_buf = (unsigned*)alloc((size_t)2 * BUFB);       // padded tagged slabs

  // zero tags (harness poisons ws with 0xAA -> would fake tags otherwise)
  hipMemsetAsync(h_buf, 0, (size_t)2 * BUFB, stream);

  cvt_bf16_v4<<<1024, 256, 0, stream>>>(W_ih, Wih_b, (long)GDIM * EMB / 4);
  cvt_bf16_v4<<<1024, 256, 0, stream>>>(W_hh, Whh_b, (long)GDIM * HID / 4);
  cvt_bf16_v4<<<2048, 256, 0, stream>>>(head_W, HW_b, (long)VOCAB * HID / 4);
  embed_gather<<<MTOT, 128, 0, stream>>>(x, emb, Aemb);

  gemm_bt<1><<<dim3(GDIM / 128, MTOT / 128), 256, 0, stream>>>(
      Aemb, Wih_b, b_ih, xg, MTOT, GDIM, EMB);

  {
    const float* xgc = xg;
    const u16* whc = Whh_b;
    void* args[] = {(void*)&xgc, (void*)&whc, (void*)&b_hh,
                    (void*)&h_buf, (void*)&h_all};
    hipLaunchCooperativeKernel((const void*)lstm_persist, dim3(NBLK), dim3(256),
                               args, 0, stream);
  }

  gemm_bt<0><<<dim3(VOCAB / 128, MTOT / 128), 256, 0, stream>>>(
      h_all, HW_b, head_b, out, MTOT, VOCAB, HID);
}